// Round 6
// baseline (482.238 us; speedup 1.0000x reference)
//
#include <hip/hip_runtime.h>
#include <cmath>

typedef __bf16 bf16x8 __attribute__((ext_vector_type(8)));
typedef float f32x4 __attribute__((ext_vector_type(4)));
typedef unsigned short us8 __attribute__((ext_vector_type(8)));

__device__ __forceinline__ unsigned short f2bf(float f) {
    union { float f; unsigned u; } x; x.f = f;
    unsigned u = x.u + 0x7FFFu + ((x.u >> 16) & 1u);
    return (unsigned short)(u >> 16);
}
__device__ __forceinline__ float bf2f(unsigned short h) {
    union { unsigned u; float f; } x; x.u = ((unsigned)h) << 16;
    return x.f;
}

// pack two f32x4 into bf16x8 (RNE via hw cvt)
__device__ __forceinline__ bf16x8 pack8b(f32x4 a, f32x4 b) {
    bf16x8 h;
    h[0] = (__bf16)a[0]; h[1] = (__bf16)a[1];
    h[2] = (__bf16)a[2]; h[3] = (__bf16)a[3];
    h[4] = (__bf16)b[0]; h[5] = (__bf16)b[1];
    h[6] = (__bf16)b[2]; h[7] = (__bf16)b[3];
    return h;
}
__device__ __forceinline__ us8 pack8(f32x4 a, f32x4 b) {
    union { bf16x8 h; us8 u; } cv;
    cv.h = pack8b(a, b);
    return cv.u;
}
// load 8 consecutive fp32, convert to bf16x8 (as us8)
__device__ __forceinline__ us8 cvt8(const float* p) {
    f32x4 a = *(const f32x4*)p;
    f32x4 b = *(const f32x4*)(p + 4);
    return pack8(a, b);
}

__device__ __forceinline__ void gl2lds16(const unsigned short* g, unsigned short* l) {
    __builtin_amdgcn_global_load_lds(
        (const __attribute__((address_space(1))) unsigned int*)g,
        (__attribute__((address_space(3))) unsigned int*)l, 16, 0, 0);
}
__device__ __forceinline__ void gl2lds16f(const float* g, float* l) {
    __builtin_amdgcn_global_load_lds(
        (const __attribute__((address_space(1))) unsigned int*)g,
        (__attribute__((address_space(3))) unsigned int*)l, 16, 0, 0);
}

// 4 weight matrices (1M floats each) in one launch; blockIdx.y selects matrix
__global__ __launch_bounds__(256)
void cvt_w4(const float* __restrict__ s0, const float* __restrict__ s1,
            const float* __restrict__ s2, const float* __restrict__ s3,
            unsigned short* __restrict__ d0, unsigned short* __restrict__ d1,
            unsigned short* __restrict__ d2, unsigned short* __restrict__ d3) {
    const float* sp[4] = {s0, s1, s2, s3};
    unsigned short* dp[4] = {d0, d1, d2, d3};
    const float* src = sp[blockIdx.y];
    unsigned short* dst = dp[blockIdx.y];
    const size_t i = ((size_t)blockIdx.x * 256 + threadIdx.x) * 8;
    *(us8*)(dst + i) = cvt8(src + i);
}

// XCD-chunked swizzle: dispatch slot s -> work w so slots with equal s%8
// (same XCD) process contiguous w. nwg=1024, 1024%8==0 -> bijective.
__device__ __forceinline__ void swz_tiles(int& m0, int& n0) {
    const int slot = blockIdx.x + (blockIdx.y << 3);
    const int w = ((slot & 7) << 7) | (slot >> 3);
    m0 = (w >> 3) << 7;
    n0 = (w & 7) << 7;
}

// ---------------------------------------------------------------------------
// Projection GEMM: Y[m,n] = sum_k A[m,k]*W[n,k] + bias[n]; M=16384,N=1024,K=1024
// A is fp32, staged DIRECTLY via global_load_lds (fire-and-forget) with an
// XOR-swizzled SOURCE column (rule-21: linear LDS dest + pre-swizzled source +
// same involution on the read) so the fp32 b128 frag reads stay bank-balanced.
// fp32->bf16 conversion happens in-register at fragment load (per-thread own
// data, no cross-wave deps). 2-deep counted pipeline: vmcnt(6) per iter.
// W: bf16 via gl2lds (pre-converted once by cvt_w4).
// MODE 1: v = exp(clamp(y)); transposed bf16 outT [B][1024][4096]; col sums->S
// MODE 2: v = y;             transposed bf16 outT
// LDS bytes: A0[0,16K) A1[16K,32K) fp32 | W0[32K,40K) W1[40K,48K) bf16
// ---------------------------------------------------------------------------
template<int MODE, bool WBF>
__global__ __launch_bounds__(256)
void gemm_proj(const float* __restrict__ A, const void* __restrict__ Wp,
               const float* __restrict__ bias,
               unsigned short* __restrict__ outT,
               float* __restrict__ S)
{
    __shared__ __align__(16) unsigned short lds[24576]; // 48KB staging | epi 17408 shorts

    const int tid = threadIdx.x;
    const int wid = tid >> 6, lane = tid & 63;
    const int quad = lane >> 4, l16 = lane & 15;
    const int waveM = wid >> 1, waveN = wid & 1;
    int m0, n0; swz_tiles(m0, n0);
    const int srow = tid >> 2, scol = (tid & 3) * 8;
    const int r4 = lane >> 2, c8 = (lane & 3) * 8;

    f32x4 acc[4][4] = {};

    if (WBF) {
        const unsigned short* W = (const unsigned short*)Wp;
        float* ldsAf = (float*)lds;            // 2 x 4096 floats
        unsigned short* ldsW = lds + 16384;    // 2 x 4096 shorts
        const int acol = ((lane & 7) ^ (lane >> 3)) * 4; // swizzled fp32 source col
#define STAGE_P2(K0, AB, WB)                                                   \
        for (int c = wid; c < 16; c += 4)                                      \
            gl2lds16f(A + (size_t)(m0 + c * 8 + (lane >> 3)) * 1024 + (K0) + acol, (AB) + c * 256); \
        for (int s = wid; s < 8; s += 4)                                       \
            gl2lds16(W + (size_t)(n0 + s * 16 + r4) * 1024 + (K0) + c8, (WB) + s * 512);
        STAGE_P2(0, ldsAf, ldsW);
        for (int t = 0; t < 32; ++t) {
            const int cur = t & 1;
            if (t < 31) {
                const int nx = cur ^ 1;
                STAGE_P2((t + 1) * 32, ldsAf + nx * 4096, ldsW + nx * 4096);
                asm volatile("s_waitcnt vmcnt(6) lgkmcnt(0)" ::: "memory"); // tile t done; t+1 in flight
            } else {
                asm volatile("s_waitcnt vmcnt(0) lgkmcnt(0)" ::: "memory");
            }
            __builtin_amdgcn_s_barrier();
            const float* fA = ldsAf + cur * 4096;
            const unsigned short* sW = ldsW + cur * 4096;
            bf16x8 af[4], bfr[4];
#pragma unroll
            for (int i = 0; i < 4; ++i) {
                const int ra = waveM * 64 + i * 16 + l16;
                f32x4 lo = *(const f32x4*)(fA + ra * 32 + (((2 * quad) ^ (ra & 7)) * 4));
                f32x4 hi = *(const f32x4*)(fA + ra * 32 + (((2 * quad + 1) ^ (ra & 7)) * 4));
                af[i] = pack8b(lo, hi);
            }
#pragma unroll
            for (int j = 0; j < 4; ++j)
                bfr[j] = *(const bf16x8*)(sW + (waveN * 64 + j * 16 + l16) * 32 + quad * 8);
#pragma unroll
            for (int i = 0; i < 4; ++i)
#pragma unroll
                for (int j = 0; j < 4; ++j)
                    acc[i][j] = __builtin_amdgcn_mfma_f32_16x16x32_bf16(af[i], bfr[j], acc[i][j], 0, 0, 0);
            asm volatile("s_waitcnt lgkmcnt(0)" ::: "memory"); // frag reads drained
            __builtin_amdgcn_s_barrier();                      // next STAGE may overwrite buf cur
        }
#undef STAGE_P2
    } else {
        // fallback: 2-buffer, full-sync, inline fp32->bf16 cvt for A and W
        const float* Wf = (const float*)Wp;
#pragma unroll
        for (int p = 0; p < 2; ++p) {
            *(us8*)(lds + (p * 64 + srow) * 32 + scol) = cvt8(A + (size_t)(m0 + p * 64 + srow) * 1024 + scol);
            *(us8*)(lds + 4096 + (p * 64 + srow) * 32 + scol) = cvt8(Wf + (size_t)(n0 + p * 64 + srow) * 1024 + scol);
        }
        __syncthreads();
        int cur = 0;
        for (int k0 = 0; k0 < 1024; k0 += 32) {
            const int nxt = cur ^ 1;
            if (k0 < 992) {
#pragma unroll
                for (int p = 0; p < 2; ++p) {
                    *(us8*)(lds + nxt * 8192 + (p * 64 + srow) * 32 + scol) =
                        cvt8(A + (size_t)(m0 + p * 64 + srow) * 1024 + k0 + 32 + scol);
                    *(us8*)(lds + nxt * 8192 + 4096 + (p * 64 + srow) * 32 + scol) =
                        cvt8(Wf + (size_t)(n0 + p * 64 + srow) * 1024 + k0 + 32 + scol);
                }
            }
            const unsigned short* ldsA = lds + cur * 8192;
            const unsigned short* ldsB = ldsA + 4096;
            bf16x8 af[4], bfr[4];
#pragma unroll
            for (int i = 0; i < 4; ++i)
                af[i] = *(const bf16x8*)(ldsA + (waveM * 64 + i * 16 + l16) * 32 + quad * 8);
#pragma unroll
            for (int j = 0; j < 4; ++j)
                bfr[j] = *(const bf16x8*)(ldsB + (waveN * 64 + j * 16 + l16) * 32 + quad * 8);
#pragma unroll
            for (int i = 0; i < 4; ++i)
#pragma unroll
                for (int j = 0; j < 4; ++j)
                    acc[i][j] = __builtin_amdgcn_mfma_f32_16x16x32_bf16(af[i], bfr[j], acc[i][j], 0, 0, 0);
            __syncthreads();
            cur = nxt;
        }
    }
    __syncthreads();

    const int b = m0 >> 12, l0 = m0 & 4095;
#pragma unroll
    for (int j = 0; j < 4; ++j) {
        const int nn = waveN * 64 + j * 16 + l16;
        const float bc = bias[n0 + nn];
        float ssum = 0.f;
#pragma unroll
        for (int i = 0; i < 4; ++i)
#pragma unroll
            for (int r = 0; r < 4; ++r) {
                const int mm = waveM * 64 + i * 16 + quad * 4 + r;
                float v = acc[i][j][r] + bc;
                if (MODE == 1) v = expf(fminf(fmaxf(v, -30.f), 30.f)); // NaN/inf firewall
                lds[nn * 136 + mm] = f2bf(v);
                ssum += v;
            }
        if (MODE == 1) {
            ssum += __shfl_xor(ssum, 16);
            ssum += __shfl_xor(ssum, 32);
            if (lane < 16)
                atomicAdd(&S[(size_t)b * 1024 + n0 + waveN * 64 + j * 16 + lane], ssum);
        }
    }
    __syncthreads();
    const int seg = (tid & 15) * 8;
#pragma unroll
    for (int it = 0; it < 8; ++it) {
        const int nn = (tid >> 4) + it * 16;
        us8 v = *(const us8*)&lds[nn * 136 + seg];
        *(us8*)(outT + ((size_t)b * 1024 + n0 + nn) * 4096 + l0 + seg) = v;
    }
}

// ---------------------------------------------------------------------------
// Context: ctxf[b][h][e][d] += sum_l Vt[b][h*64+e][l] * Et[b][h*64+d][l]
// reg-prefetch double-buffer; grid (8,16,4) -> 512 blocks, 16 K-iters
// ---------------------------------------------------------------------------
__global__ __launch_bounds__(256)
void ctx_kernel(const unsigned short* __restrict__ Vt,
                const unsigned short* __restrict__ Et,
                float* __restrict__ ctxf)
{
    __shared__ __align__(16) unsigned short lds[8192];

    const int tid = threadIdx.x;
    const int wid = tid >> 6, lane = tid & 63;
    const int quad = lane >> 4, l16 = lane & 15;
    const int b = blockIdx.z, h = blockIdx.y;
    const int lbase = blockIdx.x * 512;

    const unsigned short* Arow = Vt + ((size_t)b * 1024 + h * 64) * 4096; // rows e
    const unsigned short* Brow = Et + ((size_t)b * 1024 + h * 64) * 4096; // rows d

    const int srow = tid >> 2;
    const int scol = (tid & 3) * 8;

    f32x4 acc[4] = {};

    {
        us8 va = *(const us8*)(Arow + (size_t)srow * 4096 + lbase + scol);
        us8 vb = *(const us8*)(Brow + (size_t)srow * 4096 + lbase + scol);
        *(us8*)(lds + srow * 32 + scol) = va;
        *(us8*)(lds + 2048 + srow * 32 + scol) = vb;
    }
    __syncthreads();

    int cur = 0;
    for (int k0 = 0; k0 < 512; k0 += 32) {
        const int nxt = cur ^ 1;
        us8 na = {}, nb = {};
        const bool pf = (k0 < 480);
        if (pf) {
            na = *(const us8*)(Arow + (size_t)srow * 4096 + lbase + k0 + 32 + scol);
            nb = *(const us8*)(Brow + (size_t)srow * 4096 + lbase + k0 + 32 + scol);
        }
        const unsigned short* ldsA = lds + cur * 4096;
        const unsigned short* ldsB = ldsA + 2048;
        bf16x8 a = *(const bf16x8*)(ldsA + (wid * 16 + l16) * 32 + quad * 8);
#pragma unroll
        for (int j = 0; j < 4; ++j) {
            bf16x8 bb = *(const bf16x8*)(ldsB + (j * 16 + l16) * 32 + quad * 8);
            acc[j] = __builtin_amdgcn_mfma_f32_16x16x32_bf16(a, bb, acc[j], 0, 0, 0);
        }
        if (pf) {
            *(us8*)(lds + nxt * 4096 + srow * 32 + scol) = na;
            *(us8*)(lds + nxt * 4096 + 2048 + srow * 32 + scol) = nb;
        }
        __syncthreads();
        cur = nxt;
    }
    float* base = ctxf + ((size_t)(b * 16 + h)) * 4096;
#pragma unroll
    for (int j = 0; j < 4; ++j)
#pragma unroll
        for (int r = 0; r < 4; ++r) {
            const int e = wid * 16 + quad * 4 + r;
            const int d = j * 16 + l16;
            atomicAdd(base + e * 64 + d, acc[j][r]);
        }
}

// ---------------------------------------------------------------------------
// Fused Q-projection + attention (two heads per 128-col tile).
// Fast path: fp32 A via swizzled gl2lds + in-register cvt (same as gemm_proj).
// LDS: staging [0,48K)B during main loop. AFTER the loop: ldsQ [0,34816)B,
// ldsC [34816,53248)B = 128 rows x 72 shorts -- ctx staged POST-loop
// (fused ctx_norm), since its region aliases the staging buffers.
// ---------------------------------------------------------------------------
template<bool WBF>
__global__ __launch_bounds__(256)
void gemm_qattn(const float* __restrict__ A, const void* __restrict__ Wp,
                const float* __restrict__ bias,
                const float* __restrict__ ctxf,
                const float* __restrict__ Sv,
                const unsigned short* __restrict__ Vt,
                const int* __restrict__ ec,
                unsigned short* __restrict__ att)
{
    __shared__ __align__(16) unsigned short lds[26624];
    unsigned short* ldsQ = lds;              // [128][136] after main loop
    unsigned short* ldsC = lds + 17408;      // [128][72] after main loop

    const int tid = threadIdx.x;
    const int wid = tid >> 6, lane = tid & 63;
    const int quad = lane >> 4, l16 = lane & 15;
    const int waveM = wid >> 1, waveN = wid & 1;
    int m0, n0; swz_tiles(m0, n0);
    const int b = m0 >> 12;
    const int srow = tid >> 2, scol = (tid & 3) * 8;
    const int r4 = lane >> 2, c8 = (lane & 3) * 8;

    f32x4 acc[4][4] = {};

    if (WBF) {
        const unsigned short* W = (const unsigned short*)Wp;
        float* ldsAf = (float*)lds;
        unsigned short* ldsW = lds + 16384;
        const int acol = ((lane & 7) ^ (lane >> 3)) * 4;
#define STAGE_Q2(K0, AB, WB)                                                   \
        for (int c = wid; c < 16; c += 4)                                      \
            gl2lds16f(A + (size_t)(m0 + c * 8 + (lane >> 3)) * 1024 + (K0) + acol, (AB) + c * 256); \
        for (int s = wid; s < 8; s += 4)                                       \
            gl2lds16(W + (size_t)(n0 + s * 16 + r4) * 1024 + (K0) + c8, (WB) + s * 512);
        STAGE_Q2(0, ldsAf, ldsW);
        for (int t = 0; t < 32; ++t) {
            const int cur = t & 1;
            if (t < 31) {
                const int nx = cur ^ 1;
                STAGE_Q2((t + 1) * 32, ldsAf + nx * 4096, ldsW + nx * 4096);
                asm volatile("s_waitcnt vmcnt(6) lgkmcnt(0)" ::: "memory");
            } else {
                asm volatile("s_waitcnt vmcnt(0) lgkmcnt(0)" ::: "memory");
            }
            __builtin_amdgcn_s_barrier();
            const float* fA = ldsAf + cur * 4096;
            const unsigned short* sW = ldsW + cur * 4096;
            bf16x8 af[4], bfr[4];
#pragma unroll
            for (int i = 0; i < 4; ++i) {
                const int ra = waveM * 64 + i * 16 + l16;
                f32x4 lo = *(const f32x4*)(fA + ra * 32 + (((2 * quad) ^ (ra & 7)) * 4));
                f32x4 hi = *(const f32x4*)(fA + ra * 32 + (((2 * quad + 1) ^ (ra & 7)) * 4));
                af[i] = pack8b(lo, hi);
            }
#pragma unroll
            for (int j = 0; j < 4; ++j)
                bfr[j] = *(const bf16x8*)(sW + (waveN * 64 + j * 16 + l16) * 32 + quad * 8);
#pragma unroll
            for (int i = 0; i < 4; ++i)
#pragma unroll
                for (int j = 0; j < 4; ++j)
                    acc[i][j] = __builtin_amdgcn_mfma_f32_16x16x32_bf16(af[i], bfr[j], acc[i][j], 0, 0, 0);
            asm volatile("s_waitcnt lgkmcnt(0)" ::: "memory");
            __builtin_amdgcn_s_barrier();
        }
#undef STAGE_Q2
    } else {
        const float* Wf = (const float*)Wp;
#pragma unroll
        for (int p = 0; p < 2; ++p) {
            *(us8*)(lds + (p * 64 + srow) * 32 + scol) = cvt8(A + (size_t)(m0 + p * 64 + srow) * 1024 + scol);
            *(us8*)(lds + 4096 + (p * 64 + srow) * 32 + scol) = cvt8(Wf + (size_t)(n0 + p * 64 + srow) * 1024 + scol);
        }
        __syncthreads();
        int cur = 0;
        for (int k0 = 0; k0 < 1024; k0 += 32) {
            const int nxt = cur ^ 1;
            if (k0 < 992) {
#pragma unroll
                for (int p = 0; p < 2; ++p) {
                    *(us8*)(lds + nxt * 8192 + (p * 64 + srow) * 32 + scol) =
                        cvt8(A + (size_t)(m0 + p * 64 + srow) * 1024 + k0 + 32 + scol);
                    *(us8*)(lds + nxt * 8192 + 4096 + (p * 64 + srow) * 32 + scol) =
                        cvt8(Wf + (size_t)(n0 + p * 64 + srow) * 1024 + k0 + 32 + scol);
                }
            }
            const unsigned short* ldsA = lds + cur * 8192;
            const unsigned short* ldsB = ldsA + 4096;
            bf16x8 af[4], bfr[4];
#pragma unroll
            for (int i = 0; i < 4; ++i)
                af[i] = *(const bf16x8*)(ldsA + (waveM * 64 + i * 16 + l16) * 32 + quad * 8);
#pragma unroll
            for (int j = 0; j < 4; ++j)
                bfr[j] = *(const bf16x8*)(ldsB + (waveN * 64 + j * 16 + l16) * 32 + quad * 8);
#pragma unroll
            for (int i = 0; i < 4; ++i)
#pragma unroll
                for (int j = 0; j < 4; ++j)
                    acc[i][j] = __builtin_amdgcn_mfma_f32_16x16x32_bf16(af[i], bfr[j], acc[i][j], 0, 0, 0);
            __syncthreads();
            cur = nxt;
        }
    }
    __syncthreads();

    { // stage normalized ctx for both heads of this tile (fused ctx_norm).
        const int e2 = tid >> 1;
        const int sg = (tid & 1) * 32;
        const int hh = (n0 >> 6) + (e2 >> 6);
        const float* srcf = ctxf + (((size_t)(b * 16) + hh) * 64 + (e2 & 63)) * 64 + sg;
        const float* Sp = Sv + (size_t)b * 1024 + hh * 64 + sg;
#pragma unroll
        for (int u = 0; u < 4; ++u) {
            f32x4 c0 = *(const f32x4*)(srcf + u * 8);
            f32x4 c1 = *(const f32x4*)(srcf + u * 8 + 4);
            union { bf16x8 h; us8 uu; } cv;
#pragma unroll
            for (int j = 0; j < 4; ++j) cv.h[j] = (__bf16)(c0[j] / Sp[u * 8 + j]);
#pragma unroll
            for (int j = 0; j < 4; ++j) cv.h[4 + j] = (__bf16)(c1[j] / Sp[u * 8 + 4 + j]);
            *(us8*)&ldsC[(size_t)e2 * 72 + sg + u * 8] = cv.uu;
        }
    }

#pragma unroll
    for (int j = 0; j < 4; ++j) {
        const int nn = waveN * 64 + j * 16 + l16;
        const float bc = bias[n0 + nn];
#pragma unroll
        for (int i = 0; i < 4; ++i)
#pragma unroll
            for (int r = 0; r < 4; ++r) {
                const int mm = waveM * 64 + i * 16 + quad * 4 + r;
                ldsQ[mm * 136 + nn] = f2bf(acc[i][j][r] + bc);
            }
    }
    __syncthreads();

    f32x4 acc2[4][4] = {};
#pragma unroll
    for (int ks = 0; ks < 64; ks += 32) {
        bf16x8 aq[4], cq[4];
#pragma unroll
        for (int i = 0; i < 4; ++i)
            aq[i] = *(const bf16x8*)&ldsQ[(waveM * 64 + i * 16 + l16) * 136 + waveN * 64 + ks + quad * 8];
#pragma unroll
        for (int j = 0; j < 4; ++j)
            cq[j] = *(const bf16x8*)&ldsC[(waveN * 64 + j * 16 + l16) * 72 + ks + quad * 8];
#pragma unroll
        for (int i = 0; i < 4; ++i)
#pragma unroll
            for (int j = 0; j < 4; ++j)
                acc2[i][j] = __builtin_amdgcn_mfma_f32_16x16x32_bf16(aq[i], cq[j], acc2[i][j], 0, 0, 0);
    }

    const int common = ec[0];
#pragma unroll
    for (int i = 0; i < 4; ++i)
#pragma unroll
        for (int j = 0; j < 4; ++j)
#pragma unroll
            for (int r = 0; r < 4; ++r) {
                const int lrow = m0 + waveM * 64 + i * 16 + quad * 4 + r;
                const int chan = n0 + waveN * 64 + j * 16 + l16;
                float vv = acc2[i][j][r];
                if (!common)
                    vv = bf2f(Vt[((size_t)(lrow >> 12) * 1024 + chan) * 4096 + (lrow & 4095)]) - vv;
                att[(size_t)lrow * 1024 + chan] = f2bf(vv);
            }
}

// ---------------------------------------------------------------------------
// Output GEMM: out[m,n] = sum_k att[m,k]*Wo[n,k] + bo[n]; out fp32.
// Unchanged from R5: A bf16 (att), 3-buffer counted-vmcnt(4) pipeline.
// ---------------------------------------------------------------------------
template<bool BF>
__global__ __launch_bounds__(256)
void gemm_out(const unsigned short* __restrict__ A, const void* __restrict__ Wp,
              const float* __restrict__ bias,
              float* __restrict__ outP)
{
    __shared__ __align__(16) unsigned short lds[24576];

    const int tid = threadIdx.x;
    const int wid = tid >> 6, lane = tid & 63;
    const int quad = lane >> 4, l16 = lane & 15;
    const int waveM = wid >> 1, waveN = wid & 1;
    int m0, n0; swz_tiles(m0, n0);
    const int srow = tid >> 2, scol = (tid & 3) * 8;
    const int r4 = lane >> 2, c8 = (lane & 3) * 8;

    f32x4 acc[4][4] = {};

    if (BF) {
        const unsigned short* W = (const unsigned short*)Wp;
#define STAGE_O(K0, BASE)                                                     \
        for (int s = wid; s < 8; s += 4) {                                    \
            const int row = s * 16 + r4;                                      \
            gl2lds16(A + (size_t)(m0 + row) * 1024 + (K0) + c8, (BASE) + s * 512);          \
            gl2lds16(W + (size_t)(n0 + row) * 1024 + (K0) + c8, (BASE) + 4096 + s * 512);   \
        }
        STAGE_O(0, lds);
        STAGE_O(32, lds + 8192);
        asm volatile("s_waitcnt vmcnt(4) lgkmcnt(0)" ::: "memory");
        __builtin_amdgcn_s_barrier();

        int cur = 0;
        for (int it = 0; it < 32; ++it) {
            if (it < 30) {
                const int st = (cur >= 1) ? cur - 1 : 2;  // (cur+2)%3
                STAGE_O((it + 2) * 32, lds + st * 8192);
            }
            const unsigned short* ldsA = lds + cur * 8192;
            const unsigned short* ldsB = ldsA + 4096;
            bf16x8 af[4], bfr[4];
#pragma unroll
            for (int i = 0; i < 4; ++i)
                af[i] = *(const bf16x8*)(ldsA + (waveM * 64 + i * 16 + l16) * 32 + quad * 8);
#pragma unroll
            for (int j = 0; j < 4; ++j)
                bfr[j] = *(const bf16x8*)(ldsB + (waveN * 64 + j * 16 + l16) * 32 + quad * 8);
#pragma unroll
            for (int i = 0; i < 4; ++i)
#pragma unroll
                for (int j = 0; j < 4; ++j)
                    acc[i][j] = __builtin_amdgcn_mfma_f32_16x16x32_bf16(af[i], bfr[j], acc[i][j], 0, 0, 0);
            if (it < 30) {
                asm volatile("s_waitcnt vmcnt(4) lgkmcnt(0)" ::: "memory");
                __builtin_amdgcn_s_barrier();
            } else if (it == 30) {
                asm volatile("s_waitcnt vmcnt(0) lgkmcnt(0)" ::: "memory");
                __builtin_amdgcn_s_barrier();
            }
            cur = (cur < 2) ? cur + 1 : 0;
        }
#undef STAGE_O
    } else {
        const float* W = (const float*)Wp;
#pragma unroll
        for (int p = 0; p < 2; ++p) {
            *(us8*)(lds + (p * 64 + srow) * 32 + scol) = *(const us8*)(A + (size_t)(m0 + p * 64 + srow) * 1024 + scol);
            *(us8*)(lds + 4096 + (p * 64 + srow) * 32 + scol) = cvt8(W + (size_t)(n0 + p * 64 + srow) * 1024 + scol);
        }
        __syncthreads();
        int cur = 0;
        for (int k0 = 0; k0 < 1024; k0 += 32) {
            const int nxt = cur ^ 1;
            if (k0 < 992) {
#pragma unroll
                for (int p = 0; p < 2; ++p) {
                    *(us8*)(lds + nxt * 8192 + (p * 64 + srow) * 32 + scol) =
                        *(const us8*)(A + (size_t)(m0 + p * 64 + srow) * 1024 + k0 + 32 + scol);
                    *(us8*)(lds + nxt * 8192 + 4096 + (p * 64 + srow) * 32 + scol) =
                        cvt8(W + (size_t)(n0 + p * 64 + srow) * 1024 + k0 + 32 + scol);
                }
            }
            const unsigned short* ldsA = lds + cur * 8192;
            const unsigned short* ldsB = ldsA + 4096;
            bf16x8 af[4], bfr[4];
#pragma unroll
            for (int i = 0; i < 4; ++i)
                af[i] = *(const bf16x8*)(ldsA + (waveM * 64 + i * 16 + l16) * 32 + quad * 8);
#pragma unroll
            for (int j = 0; j < 4; ++j)
                bfr[j] = *(const bf16x8*)(ldsB + (waveN * 64 + j * 16 + l16) * 32 + quad * 8);
#pragma unroll
            for (int i = 0; i < 4; ++i)
#pragma unroll
                for (int j = 0; j < 4; ++j)
                    acc[i][j] = __builtin_amdgcn_mfma_f32_16x16x32_bf16(af[i], bfr[j], acc[i][j], 0, 0, 0);
            __syncthreads();
            cur = nxt;
        }
    }

#pragma unroll
    for (int j = 0; j < 4; ++j) {
        const int col = n0 + waveN * 64 + j * 16 + l16;
        const float bc = bias[col];
#pragma unroll
        for (int i = 0; i < 4; ++i)
#pragma unroll
            for (int r = 0; r < 4; ++r) {
                const int row = m0 + waveM * 64 + i * 16 + quad * 4 + r;
                outP[(size_t)row * 1024 + col] = acc[i][j][r] + bc;
            }
    }
}

// ---------------------------------------------------------------------------
extern "C" void kernel_launch(void* const* d_in, const int* in_sizes, int n_in,
                              void* d_out, int out_size, void* d_ws, size_t ws_size,
                              hipStream_t stream)
{
    const float* q  = (const float*)d_in[0];
    const float* k  = (const float*)d_in[1];
    const float* v  = (const float*)d_in[2];
    const float* Wq = (const float*)d_in[3];
    const float* bq = (const float*)d_in[4];
    const float* Wk = (const float*)d_in[5];
    const float* bk = (const float*)d_in[6];
    const float* Wv = (const float*)d_in[7];
    const float* bv = (const float*)d_in[8];
    const float* Wo = (const float*)d_in[9];
    const float* bo = (const float*)d_in[10];
    const int* ec   = (const int*)d_in[11];

    char* ws = (char*)d_ws;
    const size_t NEED_FAST = 76562432; // Et+Vt+W*4+ctxf+S
    const dim3 gblk(8, 128, 1);
    const dim3 gctx(8, 16, 4);

    if (ws_size >= NEED_FAST) {
        unsigned short* Et   = (unsigned short*)(ws);                 // 33.55 MB
        unsigned short* Vt   = (unsigned short*)(ws + 33554432);      // 33.55 MB
        unsigned short* Wkb  = (unsigned short*)(ws + 67108864);      // 2 MB
        unsigned short* Wvb  = (unsigned short*)(ws + 69206016);      // 2 MB
        unsigned short* Wqb  = (unsigned short*)(ws + 71303168);      // 2 MB
        unsigned short* Wob  = (unsigned short*)(ws + 73400320);      // 2 MB
        float*          ctxf = (float*)(ws + 75497472);               // 1 MB
        float*          S    = (float*)(ws + 76546048);               // 16 KB
        unsigned short* att  = Et;                                    // alias (Et dead after ctx)

        hipMemsetAsync(S, 0, 4096 * sizeof(float), stream);
        hipMemsetAsync(ctxf, 0, 4 * 16 * 64 * 64 * sizeof(float), stream);

        cvt_w4<<<dim3(512, 4), 256, 0, stream>>>(Wk, Wv, Wq, Wo, Wkb, Wvb, Wqb, Wob);

        gemm_proj<1, true><<<gblk, 256, 0, stream>>>(k, Wkb, bk, Et, S);
        gemm_proj<2, true><<<gblk, 256, 0, stream>>>(v, Wvb, bv, Vt, nullptr);

        ctx_kernel<<<gctx, 256, 0, stream>>>(Vt, Et, ctxf);

        gemm_qattn<true><<<gblk, 256, 0, stream>>>(q, Wqb, bq, ctxf, S, Vt, ec, att);

        gemm_out<true><<<gblk, 256, 0, stream>>>(att, Wob, bo, (float*)d_out);
    } else {
        // fallback: all-fp32-input path (68.7 MB)
        unsigned short* Et   = (unsigned short*)(ws);
        unsigned short* Vt   = (unsigned short*)(ws + 33554432);
        float*          ctxf = (float*)(ws + 67108864);
        float*          S    = (float*)(ws + 68157440);
        unsigned short* att  = Et;

        hipMemsetAsync(S, 0, 4096 * sizeof(float), stream);
        hipMemsetAsync(ctxf, 0, 4 * 16 * 64 * 64 * sizeof(float), stream);

        gemm_proj<1, false><<<gblk, 256, 0, stream>>>(k, Wk, bk, Et, S);
        gemm_proj<2, false><<<gblk, 256, 0, stream>>>(v, Wv, bv, Vt, nullptr);
        ctx_kernel<<<gctx, 256, 0, stream>>>(Vt, Et, ctxf);
        gemm_qattn<false><<<gblk, 256, 0, stream>>>(q, Wq, bq, ctxf, S, Vt, ec, att);
        gemm_out<false><<<gblk, 256, 0, stream>>>(att, Wo, bo, (float*)d_out);
    }
}

// Round 7
// 472.915 us; speedup vs baseline: 1.0197x; 1.0197x over previous
//
#include <hip/hip_runtime.h>
#include <cmath>

typedef __bf16 bf16x8 __attribute__((ext_vector_type(8)));
typedef float f32x4 __attribute__((ext_vector_type(4)));
typedef unsigned short us8 __attribute__((ext_vector_type(8)));

__device__ __forceinline__ unsigned short f2bf(float f) {
    union { float f; unsigned u; } x; x.f = f;
    unsigned u = x.u + 0x7FFFu + ((x.u >> 16) & 1u);
    return (unsigned short)(u >> 16);
}
__device__ __forceinline__ float bf2f(unsigned short h) {
    union { unsigned u; float f; } x; x.u = ((unsigned)h) << 16;
    return x.f;
}

// pack two f32x4 into bf16x8 (RNE via hw cvt)
__device__ __forceinline__ us8 pack8(f32x4 a, f32x4 b) {
    union { bf16x8 h; us8 u; } cv;
    cv.h[0] = (__bf16)a[0]; cv.h[1] = (__bf16)a[1];
    cv.h[2] = (__bf16)a[2]; cv.h[3] = (__bf16)a[3];
    cv.h[4] = (__bf16)b[0]; cv.h[5] = (__bf16)b[1];
    cv.h[6] = (__bf16)b[2]; cv.h[7] = (__bf16)b[3];
    return cv.u;
}
// load 8 consecutive fp32, convert to bf16x8 (as us8)
__device__ __forceinline__ us8 cvt8(const float* p) {
    f32x4 a = *(const f32x4*)p;
    f32x4 b = *(const f32x4*)(p + 4);
    return pack8(a, b);
}

__device__ __forceinline__ void gl2lds16(const unsigned short* g, unsigned short* l) {
    __builtin_amdgcn_global_load_lds(
        (const __attribute__((address_space(1))) unsigned int*)g,
        (__attribute__((address_space(3))) unsigned int*)l, 16, 0, 0);
}

// fp32 -> bf16 elementwise, 8 elems/thread, exact-size grid
__global__ __launch_bounds__(256)
void cvt_kernel(const float* __restrict__ src, unsigned short* __restrict__ dst) {
    const size_t i = ((size_t)blockIdx.x * 256 + threadIdx.x) * 8;
    *(us8*)(dst + i) = cvt8(src + i);
}

// 4 weight matrices (1M floats each) in one launch; blockIdx.y selects matrix
__global__ __launch_bounds__(256)
void cvt_w4(const float* __restrict__ s0, const float* __restrict__ s1,
            const float* __restrict__ s2, const float* __restrict__ s3,
            unsigned short* __restrict__ d0, unsigned short* __restrict__ d1,
            unsigned short* __restrict__ d2, unsigned short* __restrict__ d3) {
    const float* sp[4] = {s0, s1, s2, s3};
    unsigned short* dp[4] = {d0, d1, d2, d3};
    const float* src = sp[blockIdx.y];
    unsigned short* dst = dp[blockIdx.y];
    const size_t i = ((size_t)blockIdx.x * 256 + threadIdx.x) * 8;
    *(us8*)(dst + i) = cvt8(src + i);
}

// ALL conversions in one launch: k,v,q (8192 blocks each) + 4 weights (512 each).
// Grid = 26624 blocks; job decoded from blockIdx.x (wave-uniform branch).
__global__ __launch_bounds__(256)
void cvt_all(const float* __restrict__ k, const float* __restrict__ v,
             const float* __restrict__ q,
             const float* __restrict__ Wk, const float* __restrict__ Wv,
             const float* __restrict__ Wq, const float* __restrict__ Wo,
             unsigned short* __restrict__ dk, unsigned short* __restrict__ dv,
             unsigned short* __restrict__ dq,
             unsigned short* __restrict__ dwk, unsigned short* __restrict__ dwv,
             unsigned short* __restrict__ dwq, unsigned short* __restrict__ dwo)
{
    const int bid = blockIdx.x;
    const float* src; unsigned short* dst; int rel;
    if (bid < 8192)       { src = k; dst = dk; rel = bid; }
    else if (bid < 16384) { src = v; dst = dv; rel = bid - 8192; }
    else if (bid < 24576) { src = q; dst = dq; rel = bid - 16384; }
    else {
        const int w = bid - 24576; const int wi = w >> 9; rel = w & 511;
        const float* wsrc[4] = {Wk, Wv, Wq, Wo};
        unsigned short* wdst[4] = {dwk, dwv, dwq, dwo};
        src = wsrc[wi]; dst = wdst[wi];
    }
    const size_t i = ((size_t)rel * 256 + threadIdx.x) * 8;
    *(us8*)(dst + i) = cvt8(src + i);
}

// XCD-chunked swizzle: dispatch slot s -> work w so slots with equal s%8
// (same XCD) process contiguous w. nwg=1024, 1024%8==0 -> bijective.
__device__ __forceinline__ void swz_tiles(int& m0, int& n0) {
    const int slot = blockIdx.x + (blockIdx.y << 3);
    const int w = ((slot & 7) << 7) | (slot >> 3);
    m0 = (w >> 3) << 7;
    n0 = (w & 7) << 7;
}

// ---------------------------------------------------------------------------
// Projection GEMM: Y[m,n] = sum_k A[m,k]*W[n,k] + bias[n]; M=16384,N=1024,K=1024
// BF path (R5-proven): 3-buffer gl2lds pipeline, counted vmcnt(4) across raw
// s_barrier (T4). bf16 A keeps the per-XCD working set L2-resident (R6 lesson:
// fp32 A = 8.4MB/XCD > 4MB L2 -> thrash).
// MODE 1: v = exp(clamp(y)); transposed bf16 outT [B][1024][4096]; col sums->S
// MODE 2: v = y;             transposed bf16 outT
// ---------------------------------------------------------------------------
template<int MODE, bool BF>
__global__ __launch_bounds__(256)
void gemm_proj(const void* __restrict__ Ap, const void* __restrict__ Wp,
               const float* __restrict__ bias,
               unsigned short* __restrict__ outT,
               float* __restrict__ S)
{
    __shared__ __align__(16) unsigned short lds[24576]; // 3x8192 staging | epi 17408

    const int tid = threadIdx.x;
    const int wid = tid >> 6, lane = tid & 63;
    const int quad = lane >> 4, l16 = lane & 15;
    const int waveM = wid >> 1, waveN = wid & 1;
    int m0, n0; swz_tiles(m0, n0);
    const int srow = tid >> 2, scol = (tid & 3) * 8;
    const int r4 = lane >> 2, c8 = (lane & 3) * 8;

    f32x4 acc[4][4] = {};

    if (BF) {
        const unsigned short* A = (const unsigned short*)Ap;
        const unsigned short* W = (const unsigned short*)Wp;
#define STAGE_P(K0, BASE)                                                     \
        for (int s = wid; s < 8; s += 4) {                                    \
            const int row = s * 16 + r4;                                      \
            gl2lds16(A + (size_t)(m0 + row) * 1024 + (K0) + c8, (BASE) + s * 512);          \
            gl2lds16(W + (size_t)(n0 + row) * 1024 + (K0) + c8, (BASE) + 4096 + s * 512);   \
        }
        STAGE_P(0, lds);
        STAGE_P(32, lds + 8192);
        asm volatile("s_waitcnt vmcnt(4) lgkmcnt(0)" ::: "memory"); // tile0 done
        __builtin_amdgcn_s_barrier();

        int cur = 0;
        for (int it = 0; it < 32; ++it) {
            if (it < 30) {
                const int st = (cur >= 1) ? cur - 1 : 2;  // (cur+2)%3
                STAGE_P((it + 2) * 32, lds + st * 8192);
            }
            const unsigned short* ldsA = lds + cur * 8192;
            const unsigned short* ldsB = ldsA + 4096;
            bf16x8 af[4], bfr[4];
#pragma unroll
            for (int i = 0; i < 4; ++i)
                af[i] = *(const bf16x8*)(ldsA + (waveM * 64 + i * 16 + l16) * 32 + quad * 8);
#pragma unroll
            for (int j = 0; j < 4; ++j)
                bfr[j] = *(const bf16x8*)(ldsB + (waveN * 64 + j * 16 + l16) * 32 + quad * 8);
#pragma unroll
            for (int i = 0; i < 4; ++i)
#pragma unroll
                for (int j = 0; j < 4; ++j)
                    acc[i][j] = __builtin_amdgcn_mfma_f32_16x16x32_bf16(af[i], bfr[j], acc[i][j], 0, 0, 0);
            if (it < 30) {
                asm volatile("s_waitcnt vmcnt(4) lgkmcnt(0)" ::: "memory"); // it+1 done, it+2 in flight
                __builtin_amdgcn_s_barrier();
            } else if (it == 30) {
                asm volatile("s_waitcnt vmcnt(0) lgkmcnt(0)" ::: "memory");
                __builtin_amdgcn_s_barrier();
            }
            cur = (cur < 2) ? cur + 1 : 0;
        }
#undef STAGE_P
    } else {
        // fallback: 2-buffer, full-sync, inline fp32->bf16 cvt
        const float* A = (const float*)Ap;
        const float* W = (const float*)Wp;
#pragma unroll
        for (int p = 0; p < 2; ++p) {
            *(us8*)(lds + (p * 64 + srow) * 32 + scol) = cvt8(A + (size_t)(m0 + p * 64 + srow) * 1024 + scol);
            *(us8*)(lds + 4096 + (p * 64 + srow) * 32 + scol) = cvt8(W + (size_t)(n0 + p * 64 + srow) * 1024 + scol);
        }
        __syncthreads();
        int cur = 0;
        for (int k0 = 0; k0 < 1024; k0 += 32) {
            const int nxt = cur ^ 1;
            if (k0 < 992) {
#pragma unroll
                for (int p = 0; p < 2; ++p) {
                    *(us8*)(lds + nxt * 8192 + (p * 64 + srow) * 32 + scol) =
                        cvt8(A + (size_t)(m0 + p * 64 + srow) * 1024 + k0 + 32 + scol);
                    *(us8*)(lds + nxt * 8192 + 4096 + (p * 64 + srow) * 32 + scol) =
                        cvt8(W + (size_t)(n0 + p * 64 + srow) * 1024 + k0 + 32 + scol);
                }
            }
            const unsigned short* ldsA = lds + cur * 8192;
            const unsigned short* ldsB = ldsA + 4096;
            bf16x8 af[4], bfr[4];
#pragma unroll
            for (int i = 0; i < 4; ++i)
                af[i] = *(const bf16x8*)(ldsA + (waveM * 64 + i * 16 + l16) * 32 + quad * 8);
#pragma unroll
            for (int j = 0; j < 4; ++j)
                bfr[j] = *(const bf16x8*)(ldsB + (waveN * 64 + j * 16 + l16) * 32 + quad * 8);
#pragma unroll
            for (int i = 0; i < 4; ++i)
#pragma unroll
                for (int j = 0; j < 4; ++j)
                    acc[i][j] = __builtin_amdgcn_mfma_f32_16x16x32_bf16(af[i], bfr[j], acc[i][j], 0, 0, 0);
            __syncthreads();
            cur = nxt;
        }
    }
    __syncthreads();

    const int b = m0 >> 12, l0 = m0 & 4095;
#pragma unroll
    for (int j = 0; j < 4; ++j) {
        const int nn = waveN * 64 + j * 16 + l16;
        const float bc = bias[n0 + nn];
        float ssum = 0.f;
#pragma unroll
        for (int i = 0; i < 4; ++i)
#pragma unroll
            for (int r = 0; r < 4; ++r) {
                const int mm = waveM * 64 + i * 16 + quad * 4 + r;
                float v = acc[i][j][r] + bc;
                if (MODE == 1) v = expf(fminf(fmaxf(v, -30.f), 30.f)); // NaN/inf firewall
                lds[nn * 136 + mm] = f2bf(v);
                ssum += v;
            }
        if (MODE == 1) {
            ssum += __shfl_xor(ssum, 16);
            ssum += __shfl_xor(ssum, 32);
            if (lane < 16)
                atomicAdd(&S[(size_t)b * 1024 + n0 + waveN * 64 + j * 16 + lane], ssum);
        }
    }
    __syncthreads();
    const int seg = (tid & 15) * 8;
#pragma unroll
    for (int it = 0; it < 8; ++it) {
        const int nn = (tid >> 4) + it * 16;
        us8 v = *(const us8*)&lds[nn * 136 + seg];
        *(us8*)(outT + ((size_t)b * 1024 + n0 + nn) * 4096 + l0 + seg) = v;
    }
}

// ---------------------------------------------------------------------------
// Context: ctxf[b][h][e][d] += sum_l Vt[b][h*64+e][l] * Et[b][h*64+d][l]
// reg-prefetch double-buffer; grid (8,16,4) -> 512 blocks, 16 K-iters
// ---------------------------------------------------------------------------
__global__ __launch_bounds__(256)
void ctx_kernel(const unsigned short* __restrict__ Vt,
                const unsigned short* __restrict__ Et,
                float* __restrict__ ctxf)
{
    __shared__ __align__(16) unsigned short lds[8192];

    const int tid = threadIdx.x;
    const int wid = tid >> 6, lane = tid & 63;
    const int quad = lane >> 4, l16 = lane & 15;
    const int b = blockIdx.z, h = blockIdx.y;
    const int lbase = blockIdx.x * 512;

    const unsigned short* Arow = Vt + ((size_t)b * 1024 + h * 64) * 4096; // rows e
    const unsigned short* Brow = Et + ((size_t)b * 1024 + h * 64) * 4096; // rows d

    const int srow = tid >> 2;
    const int scol = (tid & 3) * 8;

    f32x4 acc[4] = {};

    {
        us8 va = *(const us8*)(Arow + (size_t)srow * 4096 + lbase + scol);
        us8 vb = *(const us8*)(Brow + (size_t)srow * 4096 + lbase + scol);
        *(us8*)(lds + srow * 32 + scol) = va;
        *(us8*)(lds + 2048 + srow * 32 + scol) = vb;
    }
    __syncthreads();

    int cur = 0;
    for (int k0 = 0; k0 < 512; k0 += 32) {
        const int nxt = cur ^ 1;
        us8 na = {}, nb = {};
        const bool pf = (k0 < 480);
        if (pf) {
            na = *(const us8*)(Arow + (size_t)srow * 4096 + lbase + k0 + 32 + scol);
            nb = *(const us8*)(Brow + (size_t)srow * 4096 + lbase + k0 + 32 + scol);
        }
        const unsigned short* ldsA = lds + cur * 4096;
        const unsigned short* ldsB = ldsA + 2048;
        bf16x8 a = *(const bf16x8*)(ldsA + (wid * 16 + l16) * 32 + quad * 8);
#pragma unroll
        for (int j = 0; j < 4; ++j) {
            bf16x8 bb = *(const bf16x8*)(ldsB + (j * 16 + l16) * 32 + quad * 8);
            acc[j] = __builtin_amdgcn_mfma_f32_16x16x32_bf16(a, bb, acc[j], 0, 0, 0);
        }
        if (pf) {
            *(us8*)(lds + nxt * 4096 + srow * 32 + scol) = na;
            *(us8*)(lds + nxt * 4096 + 2048 + srow * 32 + scol) = nb;
        }
        __syncthreads();
        cur = nxt;
    }
    float* base = ctxf + ((size_t)(b * 16 + h)) * 4096;
#pragma unroll
    for (int j = 0; j < 4; ++j)
#pragma unroll
        for (int r = 0; r < 4; ++r) {
            const int e = wid * 16 + quad * 4 + r;
            const int d = j * 16 + l16;
            atomicAdd(base + e * 64 + d, acc[j][r]);
        }
}

// ---------------------------------------------------------------------------
// Fused Q-projection + attention (two heads per 128-col tile).
// BF path: 3-buffer counted-vmcnt pipeline (same as gemm_proj).
// LDS: staging [0,24576) shorts during main loop. AFTER the loop:
// ldsQ [0,17408), ldsC [17408,26624) = 128 x 72 shorts, staged post-loop
// (fused ctx_norm) since its region aliases staging buffer 2+.
// ---------------------------------------------------------------------------
template<bool BF>
__global__ __launch_bounds__(256)
void gemm_qattn(const void* __restrict__ Ap, const void* __restrict__ Wp,
                const float* __restrict__ bias,
                const float* __restrict__ ctxf,
                const float* __restrict__ Sv,
                const unsigned short* __restrict__ Vt,
                const int* __restrict__ ec,
                unsigned short* __restrict__ att)
{
    __shared__ __align__(16) unsigned short lds[26624];
    unsigned short* ldsQ = lds;              // [128][136] after main loop
    unsigned short* ldsC = lds + 17408;      // [128][72] after main loop

    const int tid = threadIdx.x;
    const int wid = tid >> 6, lane = tid & 63;
    const int quad = lane >> 4, l16 = lane & 15;
    const int waveM = wid >> 1, waveN = wid & 1;
    int m0, n0; swz_tiles(m0, n0);
    const int b = m0 >> 12;
    const int srow = tid >> 2, scol = (tid & 3) * 8;
    const int r4 = lane >> 2, c8 = (lane & 3) * 8;

    f32x4 acc[4][4] = {};

    if (BF) {
        const unsigned short* A = (const unsigned short*)Ap;
        const unsigned short* W = (const unsigned short*)Wp;
#define STAGE_Q(K0, BASE)                                                     \
        for (int s = wid; s < 8; s += 4) {                                    \
            const int row = s * 16 + r4;                                      \
            gl2lds16(A + (size_t)(m0 + row) * 1024 + (K0) + c8, (BASE) + s * 512);          \
            gl2lds16(W + (size_t)(n0 + row) * 1024 + (K0) + c8, (BASE) + 4096 + s * 512);   \
        }
        STAGE_Q(0, lds);
        STAGE_Q(32, lds + 8192);
        asm volatile("s_waitcnt vmcnt(4) lgkmcnt(0)" ::: "memory");
        __builtin_amdgcn_s_barrier();

        int cur = 0;
        for (int it = 0; it < 32; ++it) {
            if (it < 30) {
                const int st = (cur >= 1) ? cur - 1 : 2;  // (cur+2)%3
                STAGE_Q((it + 2) * 32, lds + st * 8192);
            }
            const unsigned short* ldsA = lds + cur * 8192;
            const unsigned short* ldsB = ldsA + 4096;
            bf16x8 af[4], bfr[4];
#pragma unroll
            for (int i = 0; i < 4; ++i)
                af[i] = *(const bf16x8*)(ldsA + (waveM * 64 + i * 16 + l16) * 32 + quad * 8);
#pragma unroll
            for (int j = 0; j < 4; ++j)
                bfr[j] = *(const bf16x8*)(ldsB + (waveN * 64 + j * 16 + l16) * 32 + quad * 8);
#pragma unroll
            for (int i = 0; i < 4; ++i)
#pragma unroll
                for (int j = 0; j < 4; ++j)
                    acc[i][j] = __builtin_amdgcn_mfma_f32_16x16x32_bf16(af[i], bfr[j], acc[i][j], 0, 0, 0);
            if (it < 30) {
                asm volatile("s_waitcnt vmcnt(4) lgkmcnt(0)" ::: "memory");
                __builtin_amdgcn_s_barrier();
            } else if (it == 30) {
                asm volatile("s_waitcnt vmcnt(0) lgkmcnt(0)" ::: "memory");
                __builtin_amdgcn_s_barrier();
            }
            cur = (cur < 2) ? cur + 1 : 0;
        }
#undef STAGE_Q
    } else {
        const float* A = (const float*)Ap;
        const float* W = (const float*)Wp;
#pragma unroll
        for (int p = 0; p < 2; ++p) {
            *(us8*)(lds + (p * 64 + srow) * 32 + scol) = cvt8(A + (size_t)(m0 + p * 64 + srow) * 1024 + scol);
            *(us8*)(lds + 4096 + (p * 64 + srow) * 32 + scol) = cvt8(W + (size_t)(n0 + p * 64 + srow) * 1024 + scol);
        }
        __syncthreads();
        int cur = 0;
        for (int k0 = 0; k0 < 1024; k0 += 32) {
            const int nxt = cur ^ 1;
            if (k0 < 992) {
#pragma unroll
                for (int p = 0; p < 2; ++p) {
                    *(us8*)(lds + nxt * 8192 + (p * 64 + srow) * 32 + scol) =
                        cvt8(A + (size_t)(m0 + p * 64 + srow) * 1024 + k0 + 32 + scol);
                    *(us8*)(lds + nxt * 8192 + 4096 + (p * 64 + srow) * 32 + scol) =
                        cvt8(W + (size_t)(n0 + p * 64 + srow) * 1024 + k0 + 32 + scol);
                }
            }
            const unsigned short* ldsA = lds + cur * 8192;
            const unsigned short* ldsB = ldsA + 4096;
            bf16x8 af[4], bfr[4];
#pragma unroll
            for (int i = 0; i < 4; ++i)
                af[i] = *(const bf16x8*)(ldsA + (waveM * 64 + i * 16 + l16) * 32 + quad * 8);
#pragma unroll
            for (int j = 0; j < 4; ++j)
                bfr[j] = *(const bf16x8*)(ldsB + (waveN * 64 + j * 16 + l16) * 32 + quad * 8);
#pragma unroll
            for (int i = 0; i < 4; ++i)
#pragma unroll
                for (int j = 0; j < 4; ++j)
                    acc[i][j] = __builtin_amdgcn_mfma_f32_16x16x32_bf16(af[i], bfr[j], acc[i][j], 0, 0, 0);
            __syncthreads();
            cur = nxt;
        }
    }
    __syncthreads();

    { // stage normalized ctx for both heads of this tile (fused ctx_norm).
        const int e2 = tid >> 1;
        const int sg = (tid & 1) * 32;
        const int hh = (n0 >> 6) + (e2 >> 6);
        const float* srcf = ctxf + (((size_t)(b * 16) + hh) * 64 + (e2 & 63)) * 64 + sg;
        const float* Sp = Sv + (size_t)b * 1024 + hh * 64 + sg;
#pragma unroll
        for (int u = 0; u < 4; ++u) {
            f32x4 c0 = *(const f32x4*)(srcf + u * 8);
            f32x4 c1 = *(const f32x4*)(srcf + u * 8 + 4);
            union { bf16x8 h; us8 uu; } cv;
#pragma unroll
            for (int j = 0; j < 4; ++j) cv.h[j] = (__bf16)(c0[j] / Sp[u * 8 + j]);
#pragma unroll
            for (int j = 0; j < 4; ++j) cv.h[4 + j] = (__bf16)(c1[j] / Sp[u * 8 + 4 + j]);
            *(us8*)&ldsC[(size_t)e2 * 72 + sg + u * 8] = cv.uu;
        }
    }

#pragma unroll
    for (int j = 0; j < 4; ++j) {
        const int nn = waveN * 64 + j * 16 + l16;
        const float bc = bias[n0 + nn];
#pragma unroll
        for (int i = 0; i < 4; ++i)
#pragma unroll
            for (int r = 0; r < 4; ++r) {
                const int mm = waveM * 64 + i * 16 + quad * 4 + r;
                ldsQ[mm * 136 + nn] = f2bf(acc[i][j][r] + bc);
            }
    }
    __syncthreads();

    f32x4 acc2[4][4] = {};
#pragma unroll
    for (int ks = 0; ks < 64; ks += 32) {
        bf16x8 aq[4], cq[4];
#pragma unroll
        for (int i = 0; i < 4; ++i)
            aq[i] = *(const bf16x8*)&ldsQ[(waveM * 64 + i * 16 + l16) * 136 + waveN * 64 + ks + quad * 8];
#pragma unroll
        for (int j = 0; j < 4; ++j)
            cq[j] = *(const bf16x8*)&ldsC[(waveN * 64 + j * 16 + l16) * 72 + ks + quad * 8];
#pragma unroll
        for (int i = 0; i < 4; ++i)
#pragma unroll
            for (int j = 0; j < 4; ++j)
                acc2[i][j] = __builtin_amdgcn_mfma_f32_16x16x32_bf16(aq[i], cq[j], acc2[i][j], 0, 0, 0);
    }

    const int common = ec[0];
#pragma unroll
    for (int i = 0; i < 4; ++i)
#pragma unroll
        for (int j = 0; j < 4; ++j)
#pragma unroll
            for (int r = 0; r < 4; ++r) {
                const int lrow = m0 + waveM * 64 + i * 16 + quad * 4 + r;
                const int chan = n0 + waveN * 64 + j * 16 + l16;
                float vv = acc2[i][j][r];
                if (!common)
                    vv = bf2f(Vt[((size_t)(lrow >> 12) * 1024 + chan) * 4096 + (lrow & 4095)]) - vv;
                att[(size_t)lrow * 1024 + chan] = f2bf(vv);
            }
}

// ---------------------------------------------------------------------------
// Output GEMM: out[m,n] = sum_k att[m,k]*Wo[n,k] + bo[n]; out fp32.
// BF path: 3-buffer counted-vmcnt pipeline.
// ---------------------------------------------------------------------------
template<bool BF>
__global__ __launch_bounds__(256)
void gemm_out(const unsigned short* __restrict__ A, const void* __restrict__ Wp,
              const float* __restrict__ bias,
              float* __restrict__ outP)
{
    __shared__ __align__(16) unsigned short lds[24576];

    const int tid = threadIdx.x;
    const int wid = tid >> 6, lane = tid & 63;
    const int quad = lane >> 4, l16 = lane & 15;
    const int waveM = wid >> 1, waveN = wid & 1;
    int m0, n0; swz_tiles(m0, n0);
    const int srow = tid >> 2, scol = (tid & 3) * 8;
    const int r4 = lane >> 2, c8 = (lane & 3) * 8;

    f32x4 acc[4][4] = {};

    if (BF) {
        const unsigned short* W = (const unsigned short*)Wp;
#define STAGE_O(K0, BASE)                                                     \
        for (int s = wid; s < 8; s += 4) {                                    \
            const int row = s * 16 + r4;                                      \
            gl2lds16(A + (size_t)(m0 + row) * 1024 + (K0) + c8, (BASE) + s * 512);          \
            gl2lds16(W + (size_t)(n0 + row) * 1024 + (K0) + c8, (BASE) + 4096 + s * 512);   \
        }
        STAGE_O(0, lds);
        STAGE_O(32, lds + 8192);
        asm volatile("s_waitcnt vmcnt(4) lgkmcnt(0)" ::: "memory");
        __builtin_amdgcn_s_barrier();

        int cur = 0;
        for (int it = 0; it < 32; ++it) {
            if (it < 30) {
                const int st = (cur >= 1) ? cur - 1 : 2;  // (cur+2)%3
                STAGE_O((it + 2) * 32, lds + st * 8192);
            }
            const unsigned short* ldsA = lds + cur * 8192;
            const unsigned short* ldsB = ldsA + 4096;
            bf16x8 af[4], bfr[4];
#pragma unroll
            for (int i = 0; i < 4; ++i)
                af[i] = *(const bf16x8*)(ldsA + (waveM * 64 + i * 16 + l16) * 32 + quad * 8);
#pragma unroll
            for (int j = 0; j < 4; ++j)
                bfr[j] = *(const bf16x8*)(ldsB + (waveN * 64 + j * 16 + l16) * 32 + quad * 8);
#pragma unroll
            for (int i = 0; i < 4; ++i)
#pragma unroll
                for (int j = 0; j < 4; ++j)
                    acc[i][j] = __builtin_amdgcn_mfma_f32_16x16x32_bf16(af[i], bfr[j], acc[i][j], 0, 0, 0);
            if (it < 30) {
                asm volatile("s_waitcnt vmcnt(4) lgkmcnt(0)" ::: "memory");
                __builtin_amdgcn_s_barrier();
            } else if (it == 30) {
                asm volatile("s_waitcnt vmcnt(0) lgkmcnt(0)" ::: "memory");
                __builtin_amdgcn_s_barrier();
            }
            cur = (cur < 2) ? cur + 1 : 0;
        }
#undef STAGE_O
    } else {
        const float* W = (const float*)Wp;
#pragma unroll
        for (int p = 0; p < 2; ++p) {
            *(us8*)(lds + (p * 64 + srow) * 32 + scol) = *(const us8*)(A + (size_t)(m0 + p * 64 + srow) * 1024 + scol);
            *(us8*)(lds + 4096 + (p * 64 + srow) * 32 + scol) = cvt8(W + (size_t)(n0 + p * 64 + srow) * 1024 + scol);
        }
        __syncthreads();
        int cur = 0;
        for (int k0 = 0; k0 < 1024; k0 += 32) {
            const int nxt = cur ^ 1;
            if (k0 < 992) {
#pragma unroll
                for (int p = 0; p < 2; ++p) {
                    *(us8*)(lds + nxt * 8192 + (p * 64 + srow) * 32 + scol) =
                        *(const us8*)(A + (size_t)(m0 + p * 64 + srow) * 1024 + k0 + 32 + scol);
                    *(us8*)(lds + nxt * 8192 + 4096 + (p * 64 + srow) * 32 + scol) =
                        cvt8(W + (size_t)(n0 + p * 64 + srow) * 1024 + k0 + 32 + scol);
                }
            }
            const unsigned short* ldsA = lds + cur * 8192;
            const unsigned short* ldsB = ldsA + 4096;
            bf16x8 af[4], bfr[4];
#pragma unroll
            for (int i = 0; i < 4; ++i)
                af[i] = *(const bf16x8*)(ldsA + (waveM * 64 + i * 16 + l16) * 32 + quad * 8);
#pragma unroll
            for (int j = 0; j < 4; ++j)
                bfr[j] = *(const bf16x8*)(ldsB + (waveN * 64 + j * 16 + l16) * 32 + quad * 8);
#pragma unroll
            for (int i = 0; i < 4; ++i)
#pragma unroll
                for (int j = 0; j < 4; ++j)
                    acc[i][j] = __builtin_amdgcn_mfma_f32_16x16x32_bf16(af[i], bfr[j], acc[i][j], 0, 0, 0);
            __syncthreads();
            cur = nxt;
        }
    }

#pragma unroll
    for (int j = 0; j < 4; ++j) {
        const int col = n0 + waveN * 64 + j * 16 + l16;
        const float bc = bias[col];
#pragma unroll
        for (int i = 0; i < 4; ++i)
#pragma unroll
            for (int r = 0; r < 4; ++r) {
                const int row = m0 + waveM * 64 + i * 16 + quad * 4 + r;
                outP[(size_t)row * 1024 + col] = acc[i][j][r] + bc;
            }
    }
}

// ---------------------------------------------------------------------------
extern "C" void kernel_launch(void* const* d_in, const int* in_sizes, int n_in,
                              void* d_out, int out_size, void* d_ws, size_t ws_size,
                              hipStream_t stream)
{
    const float* q  = (const float*)d_in[0];
    const float* k  = (const float*)d_in[1];
    const float* v  = (const float*)d_in[2];
    const float* Wq = (const float*)d_in[3];
    const float* bq = (const float*)d_in[4];
    const float* Wk = (const float*)d_in[5];
    const float* bk = (const float*)d_in[6];
    const float* Wv = (const float*)d_in[7];
    const float* bv = (const float*)d_in[8];
    const float* Wo = (const float*)d_in[9];
    const float* bo = (const float*)d_in[10];
    const int* ec   = (const int*)d_in[11];

    char* ws = (char*)d_ws;
    const size_t NEED_MEGA = 177225728; // Abk+Abv+Abq+Et+Vt+W*4+ctxf+S
    const size_t NEED_FAST = 110641152; // Ab+Et+Vt+W*4+ctxf+S
    const dim3 gblk(8, 128, 1);
    const dim3 gctx(8, 16, 4);

    if (ws_size >= NEED_MEGA) {
        // 7-dispatch path: one cvt_all handles every fp32->bf16 conversion.
        unsigned short* Abk  = (unsigned short*)(ws);                 // 33.55 MB
        unsigned short* Abv  = (unsigned short*)(ws + 33554432);      // 33.55 MB
        unsigned short* Abq  = (unsigned short*)(ws + 67108864);      // 33.55 MB
        unsigned short* Et   = (unsigned short*)(ws + 100663296);     // 33.55 MB
        unsigned short* Vt   = (unsigned short*)(ws + 134217728);     // 33.55 MB
        unsigned short* Wkb  = (unsigned short*)(ws + 167772160);     // 2 MB
        unsigned short* Wvb  = (unsigned short*)(ws + 169869312);     // 2 MB
        unsigned short* Wqb  = (unsigned short*)(ws + 171966464);     // 2 MB
        unsigned short* Wob  = (unsigned short*)(ws + 174063616);     // 2 MB
        float*          ctxf = (float*)(ws + 176160768);              // 1 MB
        float*          S    = (float*)(ws + 177209344);              // 16 KB (adjacent to ctxf)
        unsigned short* att  = Et;                                    // alias (Et dead after ctx)

        hipMemsetAsync(ctxf, 0, 1048576 + 16384, stream);             // ctxf + S in one memset

        cvt_all<<<26624, 256, 0, stream>>>(k, v, q, Wk, Wv, Wq, Wo,
                                           Abk, Abv, Abq, Wkb, Wvb, Wqb, Wob);

        gemm_proj<1, true><<<gblk, 256, 0, stream>>>(Abk, Wkb, bk, Et, S);
        gemm_proj<2, true><<<gblk, 256, 0, stream>>>(Abv, Wvb, bv, Vt, nullptr);
        ctx_kernel<<<gctx, 256, 0, stream>>>(Vt, Et, ctxf);
        gemm_qattn<true><<<gblk, 256, 0, stream>>>(Abq, Wqb, bq, ctxf, S, Vt, ec, att);
        gemm_out<true><<<gblk, 256, 0, stream>>>(att, Wob, bo, (float*)d_out);
    } else if (ws_size >= NEED_FAST) {
        // R5-proven path: single reused Ab buffer, 3 cvt passes.
        unsigned short* Ab   = (unsigned short*)(ws);                 // 33.55 MB (reused k,v,q)
        unsigned short* Et   = (unsigned short*)(ws + 33554432);      // 33.55 MB
        unsigned short* Vt   = (unsigned short*)(ws + 67108864);      // 33.55 MB
        unsigned short* Wkb  = (unsigned short*)(ws + 100663296);     // 2 MB
        unsigned short* Wvb  = (unsigned short*)(ws + 102760448);     // 2 MB
        unsigned short* Wqb  = (unsigned short*)(ws + 104857600);     // 2 MB
        unsigned short* Wob  = (unsigned short*)(ws + 106954752);     // 2 MB
        float*          ctxf = (float*)(ws + 109051904);              // 1 MB
        float*          S    = (float*)(ws + 110100480);              // 16 KB (adjacent to ctxf)
        unsigned short* att  = Et;                                    // alias (Et dead after ctx)

        hipMemsetAsync(ctxf, 0, 1048576 + 16384, stream);             // ctxf + S in one memset

        cvt_w4<<<dim3(512, 4), 256, 0, stream>>>(Wk, Wv, Wq, Wo, Wkb, Wvb, Wqb, Wob);

        cvt_kernel<<<8192, 256, 0, stream>>>(k, Ab);
        gemm_proj<1, true><<<gblk, 256, 0, stream>>>(Ab, Wkb, bk, Et, S);

        cvt_kernel<<<8192, 256, 0, stream>>>(v, Ab);
        gemm_proj<2, true><<<gblk, 256, 0, stream>>>(Ab, Wvb, bv, Vt, nullptr);

        ctx_kernel<<<gctx, 256, 0, stream>>>(Vt, Et, ctxf);

        cvt_kernel<<<8192, 256, 0, stream>>>(q, Ab);
        gemm_qattn<true><<<gblk, 256, 0, stream>>>(Ab, Wqb, bq, ctxf, S, Vt, ec, att);

        gemm_out<true><<<gblk, 256, 0, stream>>>(att, Wob, bo, (float*)d_out);
    } else {
        // fallback: all-fp32-input path (68.7 MB)
        unsigned short* Et   = (unsigned short*)(ws);
        unsigned short* Vt   = (unsigned short*)(ws + 33554432);
        float*          ctxf = (float*)(ws + 67108864);
        float*          S    = (float*)(ws + 68157440);
        unsigned short* att  = Et;

        hipMemsetAsync(ctxf, 0, 1048576 + 16384, stream);

        gemm_proj<1, false><<<gblk, 256, 0, stream>>>(k, Wk, bk, Et, S);
        gemm_proj<2, false><<<gblk, 256, 0, stream>>>(v, Wv, bv, Vt, nullptr);
        ctx_kernel<<<gctx, 256, 0, stream>>>(Vt, Et, ctxf);
        gemm_qattn<false><<<gblk, 256, 0, stream>>>(q, Wq, bq, ctxf, S, Vt, ec, att);
        gemm_out<false><<<gblk, 256, 0, stream>>>(att, Wo, bo, (float*)d_out);
    }
}

// Round 8
// 454.022 us; speedup vs baseline: 1.0621x; 1.0416x over previous
//
#include <hip/hip_runtime.h>
#include <cmath>

typedef __bf16 bf16x8 __attribute__((ext_vector_type(8)));
typedef float f32x4 __attribute__((ext_vector_type(4)));
typedef unsigned short us8 __attribute__((ext_vector_type(8)));

__device__ __forceinline__ unsigned short f2bf(float f) {
    union { float f; unsigned u; } x; x.f = f;
    unsigned u = x.u + 0x7FFFu + ((x.u >> 16) & 1u);
    return (unsigned short)(u >> 16);
}
__device__ __forceinline__ float bf2f(unsigned short h) {
    union { unsigned u; float f; } x; x.u = ((unsigned)h) << 16;
    return x.f;
}

// pack two f32x4 into bf16x8 (RNE via hw cvt)
__device__ __forceinline__ us8 pack8(f32x4 a, f32x4 b) {
    union { bf16x8 h; us8 u; } cv;
    cv.h[0] = (__bf16)a[0]; cv.h[1] = (__bf16)a[1];
    cv.h[2] = (__bf16)a[2]; cv.h[3] = (__bf16)a[3];
    cv.h[4] = (__bf16)b[0]; cv.h[5] = (__bf16)b[1];
    cv.h[6] = (__bf16)b[2]; cv.h[7] = (__bf16)b[3];
    return cv.u;
}
// load 8 consecutive fp32, convert to bf16x8 (as us8)
__device__ __forceinline__ us8 cvt8(const float* p) {
    f32x4 a = *(const f32x4*)p;
    f32x4 b = *(const f32x4*)(p + 4);
    return pack8(a, b);
}

__device__ __forceinline__ void gl2lds16(const unsigned short* g, unsigned short* l) {
    __builtin_amdgcn_global_load_lds(
        (const __attribute__((address_space(1))) unsigned int*)g,
        (__attribute__((address_space(3))) unsigned int*)l, 16, 0, 0);
}

// fp32 -> bf16, ILP'd: 64 elems/thread as 8 us8-chunks; all 16 f32x4 loads
// issued before converts/stores (deep in-flight pipeline -> BW-bound not
// latency-bound; R7 one-shot version measured 2.4 TB/s = 38% of ceiling).
// Per-iteration wave access = contiguous 2KB (tid*8 within a 2048-elem slab).
// Grid: 1024 blocks x 256 thr x 64 elems = 16,777,216 = 4*4096*1024.
__global__ __launch_bounds__(256)
void cvt_kernel(const float* __restrict__ src, unsigned short* __restrict__ dst) {
    const size_t base = (size_t)blockIdx.x * 16384 + threadIdx.x * 8;
    f32x4 a[8], b[8];
#pragma unroll
    for (int u = 0; u < 8; ++u) {
        const float* p = src + base + u * 2048;
        a[u] = *(const f32x4*)p;
        b[u] = *(const f32x4*)(p + 4);
    }
#pragma unroll
    for (int u = 0; u < 8; ++u)
        *(us8*)(dst + base + u * 2048) = pack8(a[u], b[u]);
}

// 4 weight matrices (1M floats each) in one launch; blockIdx.y selects matrix
__global__ __launch_bounds__(256)
void cvt_w4(const float* __restrict__ s0, const float* __restrict__ s1,
            const float* __restrict__ s2, const float* __restrict__ s3,
            unsigned short* __restrict__ d0, unsigned short* __restrict__ d1,
            unsigned short* __restrict__ d2, unsigned short* __restrict__ d3) {
    const float* sp[4] = {s0, s1, s2, s3};
    unsigned short* dp[4] = {d0, d1, d2, d3};
    const float* src = sp[blockIdx.y];
    unsigned short* dst = dp[blockIdx.y];
    const size_t i = ((size_t)blockIdx.x * 256 + threadIdx.x) * 8;
    *(us8*)(dst + i) = cvt8(src + i);
}

// XCD-chunked swizzle: dispatch slot s -> work w so slots with equal s%8
// (same XCD) process contiguous w. nwg=1024, 1024%8==0 -> bijective.
__device__ __forceinline__ void swz_tiles(int& m0, int& n0) {
    const int slot = blockIdx.x + (blockIdx.y << 3);
    const int w = ((slot & 7) << 7) | (slot >> 3);
    m0 = (w >> 3) << 7;
    n0 = (w & 7) << 7;
}

// ---------------------------------------------------------------------------
// Projection GEMM: Y[m,n] = sum_k A[m,k]*W[n,k] + bias[n]; M=16384,N=1024,K=1024
// BF path (R5-proven, 449us build): 3-buffer gl2lds pipeline, counted vmcnt(4)
// across raw s_barrier (T4). bf16 A keeps the per-XCD working set L2-resident
// (R6 lesson: fp32 A = 8.4MB/XCD > 4MB L2 -> thrash).
// MODE 1: v = exp(clamp(y)); transposed bf16 outT [B][1024][4096]; col sums->S
// MODE 2: v = y;             transposed bf16 outT
// ---------------------------------------------------------------------------
template<int MODE, bool BF>
__global__ __launch_bounds__(256)
void gemm_proj(const void* __restrict__ Ap, const void* __restrict__ Wp,
               const float* __restrict__ bias,
               unsigned short* __restrict__ outT,
               float* __restrict__ S)
{
    __shared__ __align__(16) unsigned short lds[24576]; // 3x8192 staging | epi 17408

    const int tid = threadIdx.x;
    const int wid = tid >> 6, lane = tid & 63;
    const int quad = lane >> 4, l16 = lane & 15;
    const int waveM = wid >> 1, waveN = wid & 1;
    int m0, n0; swz_tiles(m0, n0);
    const int srow = tid >> 2, scol = (tid & 3) * 8;
    const int r4 = lane >> 2, c8 = (lane & 3) * 8;

    f32x4 acc[4][4] = {};

    if (BF) {
        const unsigned short* A = (const unsigned short*)Ap;
        const unsigned short* W = (const unsigned short*)Wp;
#define STAGE_P(K0, BASE)                                                     \
        for (int s = wid; s < 8; s += 4) {                                    \
            const int row = s * 16 + r4;                                      \
            gl2lds16(A + (size_t)(m0 + row) * 1024 + (K0) + c8, (BASE) + s * 512);          \
            gl2lds16(W + (size_t)(n0 + row) * 1024 + (K0) + c8, (BASE) + 4096 + s * 512);   \
        }
        STAGE_P(0, lds);
        STAGE_P(32, lds + 8192);
        asm volatile("s_waitcnt vmcnt(4) lgkmcnt(0)" ::: "memory"); // tile0 done
        __builtin_amdgcn_s_barrier();

        int cur = 0;
        for (int it = 0; it < 32; ++it) {
            if (it < 30) {
                const int st = (cur >= 1) ? cur - 1 : 2;  // (cur+2)%3
                STAGE_P((it + 2) * 32, lds + st * 8192);
            }
            const unsigned short* ldsA = lds + cur * 8192;
            const unsigned short* ldsB = ldsA + 4096;
            bf16x8 af[4], bfr[4];
#pragma unroll
            for (int i = 0; i < 4; ++i)
                af[i] = *(const bf16x8*)(ldsA + (waveM * 64 + i * 16 + l16) * 32 + quad * 8);
#pragma unroll
            for (int j = 0; j < 4; ++j)
                bfr[j] = *(const bf16x8*)(ldsB + (waveN * 64 + j * 16 + l16) * 32 + quad * 8);
#pragma unroll
            for (int i = 0; i < 4; ++i)
#pragma unroll
                for (int j = 0; j < 4; ++j)
                    acc[i][j] = __builtin_amdgcn_mfma_f32_16x16x32_bf16(af[i], bfr[j], acc[i][j], 0, 0, 0);
            if (it < 30) {
                asm volatile("s_waitcnt vmcnt(4) lgkmcnt(0)" ::: "memory"); // it+1 done, it+2 in flight
                __builtin_amdgcn_s_barrier();
            } else if (it == 30) {
                asm volatile("s_waitcnt vmcnt(0) lgkmcnt(0)" ::: "memory");
                __builtin_amdgcn_s_barrier();
            }
            cur = (cur < 2) ? cur + 1 : 0;
        }
#undef STAGE_P
    } else {
        // fallback: 2-buffer, full-sync, inline fp32->bf16 cvt
        const float* A = (const float*)Ap;
        const float* W = (const float*)Wp;
#pragma unroll
        for (int p = 0; p < 2; ++p) {
            *(us8*)(lds + (p * 64 + srow) * 32 + scol) = cvt8(A + (size_t)(m0 + p * 64 + srow) * 1024 + scol);
            *(us8*)(lds + 4096 + (p * 64 + srow) * 32 + scol) = cvt8(W + (size_t)(n0 + p * 64 + srow) * 1024 + scol);
        }
        __syncthreads();
        int cur = 0;
        for (int k0 = 0; k0 < 1024; k0 += 32) {
            const int nxt = cur ^ 1;
            if (k0 < 992) {
#pragma unroll
                for (int p = 0; p < 2; ++p) {
                    *(us8*)(lds + nxt * 8192 + (p * 64 + srow) * 32 + scol) =
                        cvt8(A + (size_t)(m0 + p * 64 + srow) * 1024 + k0 + 32 + scol);
                    *(us8*)(lds + nxt * 8192 + 4096 + (p * 64 + srow) * 32 + scol) =
                        cvt8(W + (size_t)(n0 + p * 64 + srow) * 1024 + k0 + 32 + scol);
                }
            }
            const unsigned short* ldsA = lds + cur * 8192;
            const unsigned short* ldsB = ldsA + 4096;
            bf16x8 af[4], bfr[4];
#pragma unroll
            for (int i = 0; i < 4; ++i)
                af[i] = *(const bf16x8*)(ldsA + (waveM * 64 + i * 16 + l16) * 32 + quad * 8);
#pragma unroll
            for (int j = 0; j < 4; ++j)
                bfr[j] = *(const bf16x8*)(ldsB + (waveN * 64 + j * 16 + l16) * 32 + quad * 8);
#pragma unroll
            for (int i = 0; i < 4; ++i)
#pragma unroll
                for (int j = 0; j < 4; ++j)
                    acc[i][j] = __builtin_amdgcn_mfma_f32_16x16x32_bf16(af[i], bfr[j], acc[i][j], 0, 0, 0);
            __syncthreads();
            cur = nxt;
        }
    }
    __syncthreads();

    const int b = m0 >> 12, l0 = m0 & 4095;
#pragma unroll
    for (int j = 0; j < 4; ++j) {
        const int nn = waveN * 64 + j * 16 + l16;
        const float bc = bias[n0 + nn];
        float ssum = 0.f;
#pragma unroll
        for (int i = 0; i < 4; ++i)
#pragma unroll
            for (int r = 0; r < 4; ++r) {
                const int mm = waveM * 64 + i * 16 + quad * 4 + r;
                float v = acc[i][j][r] + bc;
                if (MODE == 1) v = expf(fminf(fmaxf(v, -30.f), 30.f)); // NaN/inf firewall
                lds[nn * 136 + mm] = f2bf(v);
                ssum += v;
            }
        if (MODE == 1) {
            ssum += __shfl_xor(ssum, 16);
            ssum += __shfl_xor(ssum, 32);
            if (lane < 16)
                atomicAdd(&S[(size_t)b * 1024 + n0 + waveN * 64 + j * 16 + lane], ssum);
        }
    }
    __syncthreads();
    const int seg = (tid & 15) * 8;
#pragma unroll
    for (int it = 0; it < 8; ++it) {
        const int nn = (tid >> 4) + it * 16;
        us8 v = *(const us8*)&lds[nn * 136 + seg];
        *(us8*)(outT + ((size_t)b * 1024 + n0 + nn) * 4096 + l0 + seg) = v;
    }
}

// ---------------------------------------------------------------------------
// Context: ctxf[b][h][e][d] += sum_l Vt[b][h*64+e][l] * Et[b][h*64+d][l]
// reg-prefetch double-buffer; grid (8,16,4) -> 512 blocks, 16 K-iters
// ---------------------------------------------------------------------------
__global__ __launch_bounds__(256)
void ctx_kernel(const unsigned short* __restrict__ Vt,
                const unsigned short* __restrict__ Et,
                float* __restrict__ ctxf)
{
    __shared__ __align__(16) unsigned short lds[8192];

    const int tid = threadIdx.x;
    const int wid = tid >> 6, lane = tid & 63;
    const int quad = lane >> 4, l16 = lane & 15;
    const int b = blockIdx.z, h = blockIdx.y;
    const int lbase = blockIdx.x * 512;

    const unsigned short* Arow = Vt + ((size_t)b * 1024 + h * 64) * 4096; // rows e
    const unsigned short* Brow = Et + ((size_t)b * 1024 + h * 64) * 4096; // rows d

    const int srow = tid >> 2;
    const int scol = (tid & 3) * 8;

    f32x4 acc[4] = {};

    {
        us8 va = *(const us8*)(Arow + (size_t)srow * 4096 + lbase + scol);
        us8 vb = *(const us8*)(Brow + (size_t)srow * 4096 + lbase + scol);
        *(us8*)(lds + srow * 32 + scol) = va;
        *(us8*)(lds + 2048 + srow * 32 + scol) = vb;
    }
    __syncthreads();

    int cur = 0;
    for (int k0 = 0; k0 < 512; k0 += 32) {
        const int nxt = cur ^ 1;
        us8 na = {}, nb = {};
        const bool pf = (k0 < 480);
        if (pf) {
            na = *(const us8*)(Arow + (size_t)srow * 4096 + lbase + k0 + 32 + scol);
            nb = *(const us8*)(Brow + (size_t)srow * 4096 + lbase + k0 + 32 + scol);
        }
        const unsigned short* ldsA = lds + cur * 4096;
        const unsigned short* ldsB = ldsA + 2048;
        bf16x8 a = *(const bf16x8*)(ldsA + (wid * 16 + l16) * 32 + quad * 8);
#pragma unroll
        for (int j = 0; j < 4; ++j) {
            bf16x8 bb = *(const bf16x8*)(ldsB + (j * 16 + l16) * 32 + quad * 8);
            acc[j] = __builtin_amdgcn_mfma_f32_16x16x32_bf16(a, bb, acc[j], 0, 0, 0);
        }
        if (pf) {
            *(us8*)(lds + nxt * 4096 + srow * 32 + scol) = na;
            *(us8*)(lds + nxt * 4096 + 2048 + srow * 32 + scol) = nb;
        }
        __syncthreads();
        cur = nxt;
    }
    float* base = ctxf + ((size_t)(b * 16 + h)) * 4096;
#pragma unroll
    for (int j = 0; j < 4; ++j)
#pragma unroll
        for (int r = 0; r < 4; ++r) {
            const int e = wid * 16 + quad * 4 + r;
            const int d = j * 16 + l16;
            atomicAdd(base + e * 64 + d, acc[j][r]);
        }
}

// ---------------------------------------------------------------------------
// Fused Q-projection + attention (two heads per 128-col tile).
// BF path: 3-buffer counted-vmcnt pipeline (same as gemm_proj).
// LDS: staging [0,24576) shorts during main loop. AFTER the loop:
// ldsQ [0,17408), ldsC [17408,26624) = 128 x 72 shorts, staged post-loop
// (fused ctx_norm) since its region aliases staging buffer 2+.
// ---------------------------------------------------------------------------
template<bool BF>
__global__ __launch_bounds__(256)
void gemm_qattn(const void* __restrict__ Ap, const void* __restrict__ Wp,
                const float* __restrict__ bias,
                const float* __restrict__ ctxf,
                const float* __restrict__ Sv,
                const unsigned short* __restrict__ Vt,
                const int* __restrict__ ec,
                unsigned short* __restrict__ att)
{
    __shared__ __align__(16) unsigned short lds[26624];
    unsigned short* ldsQ = lds;              // [128][136] after main loop
    unsigned short* ldsC = lds + 17408;      // [128][72] after main loop

    const int tid = threadIdx.x;
    const int wid = tid >> 6, lane = tid & 63;
    const int quad = lane >> 4, l16 = lane & 15;
    const int waveM = wid >> 1, waveN = wid & 1;
    int m0, n0; swz_tiles(m0, n0);
    const int b = m0 >> 12;
    const int srow = tid >> 2, scol = (tid & 3) * 8;
    const int r4 = lane >> 2, c8 = (lane & 3) * 8;

    f32x4 acc[4][4] = {};

    if (BF) {
        const unsigned short* A = (const unsigned short*)Ap;
        const unsigned short* W = (const unsigned short*)Wp;
#define STAGE_Q(K0, BASE)                                                     \
        for (int s = wid; s < 8; s += 4) {                                    \
            const int row = s * 16 + r4;                                      \
            gl2lds16(A + (size_t)(m0 + row) * 1024 + (K0) + c8, (BASE) + s * 512);          \
            gl2lds16(W + (size_t)(n0 + row) * 1024 + (K0) + c8, (BASE) + 4096 + s * 512);   \
        }
        STAGE_Q(0, lds);
        STAGE_Q(32, lds + 8192);
        asm volatile("s_waitcnt vmcnt(4) lgkmcnt(0)" ::: "memory");
        __builtin_amdgcn_s_barrier();

        int cur = 0;
        for (int it = 0; it < 32; ++it) {
            if (it < 30) {
                const int st = (cur >= 1) ? cur - 1 : 2;  // (cur+2)%3
                STAGE_Q((it + 2) * 32, lds + st * 8192);
            }
            const unsigned short* ldsA = lds + cur * 8192;
            const unsigned short* ldsB = ldsA + 4096;
            bf16x8 af[4], bfr[4];
#pragma unroll
            for (int i = 0; i < 4; ++i)
                af[i] = *(const bf16x8*)(ldsA + (waveM * 64 + i * 16 + l16) * 32 + quad * 8);
#pragma unroll
            for (int j = 0; j < 4; ++j)
                bfr[j] = *(const bf16x8*)(ldsB + (waveN * 64 + j * 16 + l16) * 32 + quad * 8);
#pragma unroll
            for (int i = 0; i < 4; ++i)
#pragma unroll
                for (int j = 0; j < 4; ++j)
                    acc[i][j] = __builtin_amdgcn_mfma_f32_16x16x32_bf16(af[i], bfr[j], acc[i][j], 0, 0, 0);
            if (it < 30) {
                asm volatile("s_waitcnt vmcnt(4) lgkmcnt(0)" ::: "memory");
                __builtin_amdgcn_s_barrier();
            } else if (it == 30) {
                asm volatile("s_waitcnt vmcnt(0) lgkmcnt(0)" ::: "memory");
                __builtin_amdgcn_s_barrier();
            }
            cur = (cur < 2) ? cur + 1 : 0;
        }
#undef STAGE_Q
    } else {
        const float* A = (const float*)Ap;
        const float* W = (const float*)Wp;
#pragma unroll
        for (int p = 0; p < 2; ++p) {
            *(us8*)(lds + (p * 64 + srow) * 32 + scol) = cvt8(A + (size_t)(m0 + p * 64 + srow) * 1024 + scol);
            *(us8*)(lds + 4096 + (p * 64 + srow) * 32 + scol) = cvt8(W + (size_t)(n0 + p * 64 + srow) * 1024 + scol);
        }
        __syncthreads();
        int cur = 0;
        for (int k0 = 0; k0 < 1024; k0 += 32) {
            const int nxt = cur ^ 1;
            if (k0 < 992) {
#pragma unroll
                for (int p = 0; p < 2; ++p) {
                    *(us8*)(lds + nxt * 8192 + (p * 64 + srow) * 32 + scol) =
                        cvt8(A + (size_t)(m0 + p * 64 + srow) * 1024 + k0 + 32 + scol);
                    *(us8*)(lds + nxt * 8192 + 4096 + (p * 64 + srow) * 32 + scol) =
                        cvt8(W + (size_t)(n0 + p * 64 + srow) * 1024 + k0 + 32 + scol);
                }
            }
            const unsigned short* ldsA = lds + cur * 8192;
            const unsigned short* ldsB = ldsA + 4096;
            bf16x8 af[4], bfr[4];
#pragma unroll
            for (int i = 0; i < 4; ++i)
                af[i] = *(const bf16x8*)(ldsA + (waveM * 64 + i * 16 + l16) * 32 + quad * 8);
#pragma unroll
            for (int j = 0; j < 4; ++j)
                bfr[j] = *(const bf16x8*)(ldsB + (waveN * 64 + j * 16 + l16) * 32 + quad * 8);
#pragma unroll
            for (int i = 0; i < 4; ++i)
#pragma unroll
                for (int j = 0; j < 4; ++j)
                    acc[i][j] = __builtin_amdgcn_mfma_f32_16x16x32_bf16(af[i], bfr[j], acc[i][j], 0, 0, 0);
            __syncthreads();
            cur = nxt;
        }
    }
    __syncthreads();

    { // stage normalized ctx for both heads of this tile (fused ctx_norm).
        const int e2 = tid >> 1;
        const int sg = (tid & 1) * 32;
        const int hh = (n0 >> 6) + (e2 >> 6);
        const float* srcf = ctxf + (((size_t)(b * 16) + hh) * 64 + (e2 & 63)) * 64 + sg;
        const float* Sp = Sv + (size_t)b * 1024 + hh * 64 + sg;
#pragma unroll
        for (int u = 0; u < 4; ++u) {
            f32x4 c0 = *(const f32x4*)(srcf + u * 8);
            f32x4 c1 = *(const f32x4*)(srcf + u * 8 + 4);
            union { bf16x8 h; us8 uu; } cv;
#pragma unroll
            for (int j = 0; j < 4; ++j) cv.h[j] = (__bf16)(c0[j] / Sp[u * 8 + j]);
#pragma unroll
            for (int j = 0; j < 4; ++j) cv.h[4 + j] = (__bf16)(c1[j] / Sp[u * 8 + 4 + j]);
            *(us8*)&ldsC[(size_t)e2 * 72 + sg + u * 8] = cv.uu;
        }
    }

#pragma unroll
    for (int j = 0; j < 4; ++j) {
        const int nn = waveN * 64 + j * 16 + l16;
        const float bc = bias[n0 + nn];
#pragma unroll
        for (int i = 0; i < 4; ++i)
#pragma unroll
            for (int r = 0; r < 4; ++r) {
                const int mm = waveM * 64 + i * 16 + quad * 4 + r;
                ldsQ[mm * 136 + nn] = f2bf(acc[i][j][r] + bc);
            }
    }
    __syncthreads();

    f32x4 acc2[4][4] = {};
#pragma unroll
    for (int ks = 0; ks < 64; ks += 32) {
        bf16x8 aq[4], cq[4];
#pragma unroll
        for (int i = 0; i < 4; ++i)
            aq[i] = *(const bf16x8*)&ldsQ[(waveM * 64 + i * 16 + l16) * 136 + waveN * 64 + ks + quad * 8];
#pragma unroll
        for (int j = 0; j < 4; ++j)
            cq[j] = *(const bf16x8*)&ldsC[(waveN * 64 + j * 16 + l16) * 72 + ks + quad * 8];
#pragma unroll
        for (int i = 0; i < 4; ++i)
#pragma unroll
            for (int j = 0; j < 4; ++j)
                acc2[i][j] = __builtin_amdgcn_mfma_f32_16x16x32_bf16(aq[i], cq[j], acc2[i][j], 0, 0, 0);
    }

    const int common = ec[0];
#pragma unroll
    for (int i = 0; i < 4; ++i)
#pragma unroll
        for (int j = 0; j < 4; ++j)
#pragma unroll
            for (int r = 0; r < 4; ++r) {
                const int lrow = m0 + waveM * 64 + i * 16 + quad * 4 + r;
                const int chan = n0 + waveN * 64 + j * 16 + l16;
                float vv = acc2[i][j][r];
                if (!common)
                    vv = bf2f(Vt[((size_t)(lrow >> 12) * 1024 + chan) * 4096 + (lrow & 4095)]) - vv;
                att[(size_t)lrow * 1024 + chan] = f2bf(vv);
            }
}

// ---------------------------------------------------------------------------
// Output GEMM: out[m,n] = sum_k att[m,k]*Wo[n,k] + bo[n]; out fp32.
// BF path: 3-buffer counted-vmcnt pipeline.
// ---------------------------------------------------------------------------
template<bool BF>
__global__ __launch_bounds__(256)
void gemm_out(const unsigned short* __restrict__ A, const void* __restrict__ Wp,
              const float* __restrict__ bias,
              float* __restrict__ outP)
{
    __shared__ __align__(16) unsigned short lds[24576];

    const int tid = threadIdx.x;
    const int wid = tid >> 6, lane = tid & 63;
    const int quad = lane >> 4, l16 = lane & 15;
    const int waveM = wid >> 1, waveN = wid & 1;
    int m0, n0; swz_tiles(m0, n0);
    const int srow = tid >> 2, scol = (tid & 3) * 8;
    const int r4 = lane >> 2, c8 = (lane & 3) * 8;

    f32x4 acc[4][4] = {};

    if (BF) {
        const unsigned short* W = (const unsigned short*)Wp;
#define STAGE_O(K0, BASE)                                                     \
        for (int s = wid; s < 8; s += 4) {                                    \
            const int row = s * 16 + r4;                                      \
            gl2lds16(A + (size_t)(m0 + row) * 1024 + (K0) + c8, (BASE) + s * 512);          \
            gl2lds16(W + (size_t)(n0 + row) * 1024 + (K0) + c8, (BASE) + 4096 + s * 512);   \
        }
        STAGE_O(0, lds);
        STAGE_O(32, lds + 8192);
        asm volatile("s_waitcnt vmcnt(4) lgkmcnt(0)" ::: "memory");
        __builtin_amdgcn_s_barrier();

        int cur = 0;
        for (int it = 0; it < 32; ++it) {
            if (it < 30) {
                const int st = (cur >= 1) ? cur - 1 : 2;  // (cur+2)%3
                STAGE_O((it + 2) * 32, lds + st * 8192);
            }
            const unsigned short* ldsA = lds + cur * 8192;
            const unsigned short* ldsB = ldsA + 4096;
            bf16x8 af[4], bfr[4];
#pragma unroll
            for (int i = 0; i < 4; ++i)
                af[i] = *(const bf16x8*)(ldsA + (waveM * 64 + i * 16 + l16) * 32 + quad * 8);
#pragma unroll
            for (int j = 0; j < 4; ++j)
                bfr[j] = *(const bf16x8*)(ldsB + (waveN * 64 + j * 16 + l16) * 32 + quad * 8);
#pragma unroll
            for (int i = 0; i < 4; ++i)
#pragma unroll
                for (int j = 0; j < 4; ++j)
                    acc[i][j] = __builtin_amdgcn_mfma_f32_16x16x32_bf16(af[i], bfr[j], acc[i][j], 0, 0, 0);
            if (it < 30) {
                asm volatile("s_waitcnt vmcnt(4) lgkmcnt(0)" ::: "memory");
                __builtin_amdgcn_s_barrier();
            } else if (it == 30) {
                asm volatile("s_waitcnt vmcnt(0) lgkmcnt(0)" ::: "memory");
                __builtin_amdgcn_s_barrier();
            }
            cur = (cur < 2) ? cur + 1 : 0;
        }
#undef STAGE_O
    } else {
        const float* W = (const float*)Wp;
#pragma unroll
        for (int p = 0; p < 2; ++p) {
            *(us8*)(lds + (p * 64 + srow) * 32 + scol) = *(const us8*)(A + (size_t)(m0 + p * 64 + srow) * 1024 + scol);
            *(us8*)(lds + 4096 + (p * 64 + srow) * 32 + scol) = cvt8(W + (size_t)(n0 + p * 64 + srow) * 1024 + scol);
        }
        __syncthreads();
        int cur = 0;
        for (int k0 = 0; k0 < 1024; k0 += 32) {
            const int nxt = cur ^ 1;
            if (k0 < 992) {
#pragma unroll
                for (int p = 0; p < 2; ++p) {
                    *(us8*)(lds + nxt * 8192 + (p * 64 + srow) * 32 + scol) =
                        *(const us8*)(A + (size_t)(m0 + p * 64 + srow) * 1024 + k0 + 32 + scol);
                    *(us8*)(lds + nxt * 8192 + 4096 + (p * 64 + srow) * 32 + scol) =
                        cvt8(W + (size_t)(n0 + p * 64 + srow) * 1024 + k0 + 32 + scol);
                }
            }
            const unsigned short* ldsA = lds + cur * 8192;
            const unsigned short* ldsB = ldsA + 4096;
            bf16x8 af[4], bfr[4];
#pragma unroll
            for (int i = 0; i < 4; ++i)
                af[i] = *(const bf16x8*)(ldsA + (waveM * 64 + i * 16 + l16) * 32 + quad * 8);
#pragma unroll
            for (int j = 0; j < 4; ++j)
                bfr[j] = *(const bf16x8*)(ldsB + (waveN * 64 + j * 16 + l16) * 32 + quad * 8);
#pragma unroll
            for (int i = 0; i < 4; ++i)
#pragma unroll
                for (int j = 0; j < 4; ++j)
                    acc[i][j] = __builtin_amdgcn_mfma_f32_16x16x32_bf16(af[i], bfr[j], acc[i][j], 0, 0, 0);
            __syncthreads();
            cur = nxt;
        }
    }

#pragma unroll
    for (int j = 0; j < 4; ++j) {
        const int col = n0 + waveN * 64 + j * 16 + l16;
        const float bc = bias[col];
#pragma unroll
        for (int i = 0; i < 4; ++i)
#pragma unroll
            for (int r = 0; r < 4; ++r) {
                const int row = m0 + waveM * 64 + i * 16 + quad * 4 + r;
                outP[(size_t)row * 1024 + col] = acc[i][j][r] + bc;
            }
    }
}

// ---------------------------------------------------------------------------
extern "C" void kernel_launch(void* const* d_in, const int* in_sizes, int n_in,
                              void* d_out, int out_size, void* d_ws, size_t ws_size,
                              hipStream_t stream)
{
    const float* q  = (const float*)d_in[0];
    const float* k  = (const float*)d_in[1];
    const float* v  = (const float*)d_in[2];
    const float* Wq = (const float*)d_in[3];
    const float* bq = (const float*)d_in[4];
    const float* Wk = (const float*)d_in[5];
    const float* bk = (const float*)d_in[6];
    const float* Wv = (const float*)d_in[7];
    const float* bv = (const float*)d_in[8];
    const float* Wo = (const float*)d_in[9];
    const float* bo = (const float*)d_in[10];
    const int* ec   = (const int*)d_in[11];

    char* ws = (char*)d_ws;
    const size_t NEED_FAST = 110641152; // Ab+Et+Vt+W*4+ctxf+S
    const dim3 gblk(8, 128, 1);
    const dim3 gctx(8, 16, 4);

    if (ws_size >= NEED_FAST) {
        // R5-proven interleaved path (producer->consumer L3 warmth) + ILP cvt.
        unsigned short* Ab   = (unsigned short*)(ws);                 // 33.55 MB (reused k,v,q)
        unsigned short* Et   = (unsigned short*)(ws + 33554432);      // 33.55 MB
        unsigned short* Vt   = (unsigned short*)(ws + 67108864);      // 33.55 MB
        unsigned short* Wkb  = (unsigned short*)(ws + 100663296);     // 2 MB
        unsigned short* Wvb  = (unsigned short*)(ws + 102760448);     // 2 MB
        unsigned short* Wqb  = (unsigned short*)(ws + 104857600);     // 2 MB
        unsigned short* Wob  = (unsigned short*)(ws + 106954752);     // 2 MB
        float*          ctxf = (float*)(ws + 109051904);              // 1 MB
        float*          S    = (float*)(ws + 110100480);              // 16 KB (adjacent to ctxf)
        unsigned short* att  = Et;                                    // alias (Et dead after ctx)

        hipMemsetAsync(ctxf, 0, 1048576 + 16384, stream);             // ctxf + S in one memset

        cvt_w4<<<dim3(512, 4), 256, 0, stream>>>(Wk, Wv, Wq, Wo, Wkb, Wvb, Wqb, Wob);

        cvt_kernel<<<1024, 256, 0, stream>>>(k, Ab);
        gemm_proj<1, true><<<gblk, 256, 0, stream>>>(Ab, Wkb, bk, Et, S);

        cvt_kernel<<<1024, 256, 0, stream>>>(v, Ab);
        gemm_proj<2, true><<<gblk, 256, 0, stream>>>(Ab, Wvb, bv, Vt, nullptr);

        ctx_kernel<<<gctx, 256, 0, stream>>>(Vt, Et, ctxf);

        cvt_kernel<<<1024, 256, 0, stream>>>(q, Ab);
        gemm_qattn<true><<<gblk, 256, 0, stream>>>(Ab, Wqb, bq, ctxf, S, Vt, ec, att);

        gemm_out<true><<<gblk, 256, 0, stream>>>(att, Wob, bo, (float*)d_out);
    } else {
        // fallback: all-fp32-input path (68.7 MB)
        unsigned short* Et   = (unsigned short*)(ws);
        unsigned short* Vt   = (unsigned short*)(ws + 33554432);
        float*          ctxf = (float*)(ws + 67108864);
        float*          S    = (float*)(ws + 68157440);
        unsigned short* att  = Et;

        hipMemsetAsync(ctxf, 0, 1048576 + 16384, stream);

        gemm_proj<1, false><<<gblk, 256, 0, stream>>>(k, Wk, bk, Et, S);
        gemm_proj<2, false><<<gblk, 256, 0, stream>>>(v, Wv, bv, Vt, nullptr);
        ctx_kernel<<<gctx, 256, 0, stream>>>(Vt, Et, ctxf);
        gemm_qattn<false><<<gblk, 256, 0, stream>>>(q, Wq, bq, ctxf, S, Vt, ec, att);
        gemm_out<false><<<gblk, 256, 0, stream>>>(att, Wo, bo, (float*)d_out);
    }
}